// Round 3
// baseline (199716.675 us; speedup 1.0000x reference)
//
#include <hip/hip_runtime.h>
#include <hip/hip_bf16.h>

#define S_LEN 8192
#define E_DIM 1024
#define H_DIM 2048
#define T_TAGS 50
#define NWG 256            // persistent workgroups for the recurrence
#define RPW (H_DIM / NWG)  // fallback path: 8 rows per WG

typedef short short8 __attribute__((ext_vector_type(8)));
typedef float floatx4 __attribute__((ext_vector_type(4)));
typedef _Float16 half8 __attribute__((ext_vector_type(8)));
typedef _Float16 half2v __attribute__((ext_vector_type(2)));
typedef unsigned int uint4a __attribute__((ext_vector_type(4)));

__device__ __forceinline__ unsigned short f2bf(float f) {
    unsigned u = __builtin_bit_cast(unsigned, f);
    unsigned r = (u + 0x7fffu + ((u >> 16) & 1u)) >> 16;
    return (unsigned short)r;
}

__device__ __forceinline__ float dot8(half8 a, half8 b, float acc) {
#if __has_builtin(__builtin_amdgcn_fdot2)
    union U { half8 v; half2v p[4]; };
    U ua; ua.v = a; U ub; ub.v = b;
    acc = __builtin_amdgcn_fdot2(ua.p[0], ub.p[0], acc, false);
    acc = __builtin_amdgcn_fdot2(ua.p[1], ub.p[1], acc, false);
    acc = __builtin_amdgcn_fdot2(ua.p[2], ub.p[2], acc, false);
    acc = __builtin_amdgcn_fdot2(ua.p[3], ub.p[3], acc, false);
#else
    #pragma unroll
    for (int i = 0; i < 8; ++i) acc += (float)a[i] * (float)b[i];
#endif
    return acc;
}

__device__ __forceinline__ float fast_tanh(float x) {
    float xc = fminf(fmaxf(x, -9.f), 9.f);
    float e = __expf(2.f * xc);
    return (e - 1.f) / (e + 1.f);
}

// Straggler re-poll of one 8-word tagged chunk (2x dwordx4). sc0 = local-L2
// scope (publish executes AT local L2 via atomic, so sc0 polls see it).
// coh=true escalation additionally tries IF scope (insurance only; the
// alternation with sc0-only rounds preserves progress either way).
// NOTE gfx950 assembler: offset: immediate must PRECEDE cache flags.
__device__ __forceinline__ void poll2(const unsigned* p, uint4a& a, uint4a& b, bool coh) {
    if (coh)
        asm volatile("global_load_dwordx4 %0, %2, off sc0 sc1\n\t"
                     "global_load_dwordx4 %1, %2, off offset:16 sc0 sc1\n\t"
                     "s_waitcnt vmcnt(0)"
                     : "=&v"(a), "=&v"(b) : "v"(p) : "memory");
    else
        asm volatile("global_load_dwordx4 %0, %2, off sc0\n\t"
                     "global_load_dwordx4 %1, %2, off offset:16 sc0\n\t"
                     "s_waitcnt vmcnt(0)"
                     : "=&v"(a), "=&v"(b) : "v"(p) : "memory");
}

#define TAGOK(A, B)                                                          \
    (((A.x >> 16) == tg) & ((A.y >> 16) == tg) & ((A.z >> 16) == tg) &       \
     ((A.w >> 16) == tg) & ((B.x >> 16) == tg) & ((B.y >> 16) == tg) &       \
     ((B.z >> 16) == tg) & ((B.w >> 16) == tg))

// Strip tags, rebuild half8, accumulate 16 row-partials for column chunk J.
#define DO_CHUNK(J, A, B)                                                    \
    do {                                                                     \
        unsigned u0 = (A.x & 0xffffu) | (A.y << 16);                         \
        unsigned u1 = (A.z & 0xffffu) | (A.w << 16);                         \
        unsigned u2 = (B.x & 0xffffu) | (B.y << 16);                         \
        unsigned u3 = (B.z & 0xffffu) | (B.w << 16);                         \
        uint4a hp; hp.x = u0; hp.y = u1; hp.z = u2; hp.w = u3;               \
        half8 hv = __builtin_bit_cast(half8, hp);                            \
        _Pragma("unroll")                                                    \
        for (int i_ = 0; i_ < 16; ++i_) acc[i_] = dot8(w[i_][J], hv, acc[i_]); \
    } while (0)

// ---------------- K0a: cast weights (W_hh->f16, W_ih->bf16, W_out->f16 padded)
__global__ __launch_bounds__(256) void cast_kernel(
        const float* __restrict__ whh, const float* __restrict__ wih,
        const float* __restrict__ wout,
        _Float16* __restrict__ whh_h, unsigned short* __restrict__ wih_b,
        _Float16* __restrict__ wout_h) {
    const int nWhh = H_DIM * H_DIM;
    const int nWih = H_DIM * E_DIM;
    const int nWout = 64 * H_DIM;
    long long i = (long long)blockIdx.x * 256 + threadIdx.x;
    if (i < nWhh) { whh_h[i] = (_Float16)whh[i]; return; }
    i -= nWhh;
    if (i < nWih) { wih_b[i] = f2bf(wih[i]); return; }
    i -= nWih;
    if (i < nWout) {
        int r = (int)(i >> 11), c = (int)(i & 2047);
        wout_h[i] = (r < T_TAGS) ? (_Float16)wout[r * H_DIM + c] : (_Float16)0.f;
    }
}

// ---------------- K0b: embedding gather -> bf16 X
__global__ __launch_bounds__(256) void embed_kernel(
        const int* __restrict__ sent, const float* __restrict__ emb,
        unsigned short* __restrict__ Xb) {
    size_t i = (size_t)blockIdx.x * 256 + threadIdx.x;
    size_t s = i >> 10, e = i & 1023;
    Xb[i] = f2bf(emb[(size_t)sent[s] * E_DIM + e]);
}

// ---------------- K1: xi = X @ W_ih^T + b_ih + b_hh   (bf16 MFMA)
__global__ __launch_bounds__(256) void xi_gemm(
        const unsigned short* __restrict__ Xb, const unsigned short* __restrict__ Wb,
        const float* __restrict__ bih, const float* __restrict__ bhh,
        float* __restrict__ xi) {
    int lane = threadIdx.x & 63;
    int w = threadIdx.x >> 6;
    int m0 = blockIdx.y * 64 + w * 16;
    int n0 = blockIdx.x * 16;
    int mi = m0 + (lane & 15);
    int ni = n0 + (lane & 15);
    int q8 = (lane >> 4) * 8;
    const short8* arow = (const short8*)(Xb + (size_t)mi * E_DIM + q8);
    const short8* brow = (const short8*)(Wb + (size_t)ni * E_DIM + q8);
    floatx4 acc = {0.f, 0.f, 0.f, 0.f};
    #pragma unroll 4
    for (int k = 0; k < E_DIM / 32; ++k) {
        short8 a = arow[k * 4];
        short8 b = brow[k * 4];
        acc = __builtin_amdgcn_mfma_f32_16x16x32_bf16(a, b, acc, 0, 0, 0);
    }
    float bias = bih[ni] + bhh[ni];
    int rbase = (lane >> 4) * 4;
    #pragma unroll
    for (int i = 0; i < 4; ++i) {
        xi[(size_t)(m0 + rbase + i) * H_DIM + ni] = acc[i] + bias;
    }
}

// ---------------- K1b: init tagged h buffers: global hpk (fallback) + 8 per-XCD
// replicas hx (fast). buf0 = (h0, tag 0); buf1 = never-matching tag.
__global__ __launch_bounds__(256) void init_hpk(
        const float* __restrict__ h0, unsigned* __restrict__ hpk,
        unsigned* __restrict__ hx) {
    int i = blockIdx.x * 256 + threadIdx.x;   // grid covers H_DIM
    if (i < H_DIM) {
        unsigned short hb = __builtin_bit_cast(unsigned short, (_Float16)h0[i]);
        unsigned pk = (unsigned)hb;           // tag 0 in high 16 bits
        hpk[i] = pk;
        hpk[H_DIM + i] = 0xFFFF0000u;
        #pragma unroll
        for (int x = 0; x < 8; ++x) {
            hx[(size_t)x * 2 * H_DIM + i] = pk;
            hx[(size_t)x * 2 * H_DIM + H_DIM + i] = 0xFFFF0000u;
        }
    }
}

// ---------------- K2: persistent sequential recurrence.
// FAST PATH (placement uniform: 32 WGs on every XCD): each XCD runs a full
// independent replica.
// ROUND-2 POST-MORTEM: publish via plain `global_store_dword sc0` (no sc1)
// dropped WRITE_SIZE 557->33 MB (locality confirmed) but cost 7.6x time:
// non-coherent stores linger in the CU write-combine/store buffer and drain
// to L2 lazily (us-scale), so same-XCD pollers spin ~57k cycles/step.
// THIS ROUND: publish = non-returning `global_atomic_swap` with NO cache
// flags. Atomics are never write-combined — they execute AT the L2 — and
// without sc1 they execute at the LOCAL XCD L2, leaving the line dirty-
// resident there: immediate visibility to same-XCD sc0 polls, still zero
// IF/HBM round trip. Everything else unchanged from round 1:
//   * poll = sc0 loads (L1-bypass, local-L2); after 24 failed rounds
//     alternate sc0 / sc0 sc1 (progress via the sc0-only rounds regardless).
//   * NO LDS staging, NO __syncthreads in the step loop; per-thread polls of
//     the exact four 8-word tagged chunks its dot-products consume, staged
//     vmcnt(6/4/2/0); tag chain carries buffer-overwrite safety.
//   * xi via register prefetch one step ahead, drained by vmcnt(0).
// FALLBACK (placement skew): round-3 global protocol, UNCHANGED (validated).
__global__ __launch_bounds__(256, 1) void rnn_seq(
        const _Float16* __restrict__ Whh, const float* __restrict__ xi,
        unsigned* __restrict__ hpk, unsigned* __restrict__ hx,
        unsigned* __restrict__ ctl, _Float16* __restrict__ rnn) {
    __shared__ __align__(16) _Float16 hlds[2][H_DIM];     // fallback only
    __shared__ float xilds[2][64];                        // fallback only
    __shared__ int sh_xcd, sh_rank, sh_fast;
    const int tid = threadIdx.x;
    const int wg = blockIdx.x;

    // ---- one-time election: discover XCD, rank within XCD, uniformity.
    // Bounded: grid=256 at 1 WG/CU on 256 CUs is co-resident (r1-r3 property),
    // and every WG increments ctl[8] exactly once -> the spin terminates.
    if (tid == 0) {
        unsigned x;
        asm volatile("s_getreg_b32 %0, hwreg(HW_REG_XCC_ID)" : "=s"(x));
        x &= 7u;
        unsigned rk = __hip_atomic_fetch_add(&ctl[x], 1u, __ATOMIC_RELAXED,
                                             __HIP_MEMORY_SCOPE_AGENT);
        __hip_atomic_fetch_add(&ctl[8], 1u, __ATOMIC_RELEASE,
                               __HIP_MEMORY_SCOPE_AGENT);
        while (__hip_atomic_load(&ctl[8], __ATOMIC_ACQUIRE,
                                 __HIP_MEMORY_SCOPE_AGENT) < (unsigned)NWG)
            __builtin_amdgcn_s_sleep(2);
        int fast = 1;
        for (int k = 0; k < 8; ++k)
            fast &= (__hip_atomic_load(&ctl[k], __ATOMIC_RELAXED,
                                       __HIP_MEMORY_SCOPE_AGENT) == 32u);
        sh_xcd = (int)x; sh_rank = (int)rk; sh_fast = fast;
    }
    __syncthreads();
    const int xcd = sh_xcd, rank = sh_rank, use_fast = sh_fast;

    if (use_fast && rank < 32) {
        // ================= FAST PATH: per-XCD replica =================
        const int lane = tid & 63;
        const int wv = tid >> 6;           // wave 0..3
        const int wgrow = rank * 64;       // this WG's 64 rows
        unsigned* hxl = hx + (size_t)xcd * 2 * H_DIM;   // local replica buffer

        // weights -> VGPRs: thread(wv,lane) holds rows wgrow+wv*16+i (i<16),
        // cols lane*8 + j*512 .. +8 (j<4). 256 VGPRs of weights.
        half8 w[16][4];
        {
            const _Float16* wb = Whh + (size_t)(wgrow + wv * 16) * H_DIM + lane * 8;
            #pragma unroll
            for (int i = 0; i < 16; ++i) {
                const half8* rp = (const half8*)(wb + (size_t)i * H_DIM);
                #pragma unroll
                for (int j = 0; j < 4; ++j) w[i][j] = rp[j * 64];
            }
        }

        // bit-reversed row owned by the butterfly's publishing lane (lane<16)
        const int lr = ((lane & 1) << 3) | (((lane >> 1) & 1) << 2) |
                       (((lane >> 2) & 1) << 1) | ((lane >> 3) & 1);
        const int myrow = wgrow + wv * 16 + lr;          // row published by this lane
        const float* xip = xi + myrow;
        unsigned xi_hold = __builtin_bit_cast(unsigned, xip[0]);   // xi[0][myrow]

        for (int t = 0; t < S_LEN; ++t) {
            const unsigned tg = (unsigned)t;
            const unsigned* pA = hxl + (size_t)(t & 1) * H_DIM + lane * 8;
            const unsigned* pB = pA + 1024;   // +4096 B: chunks j=2,3
            const float* xin = xip + (size_t)(t + 1 < S_LEN ? t + 1 : t) * H_DIM;
            unsigned xiu;
            uint4a a0, b0, a1, b1, a2, b2, a3, b3;
            // Issue xi[t+1] prefetch + all 4 chunk-pair polls in fixed order.
            // vmcnt staging below relies only on "all but last N issued are
            // complete" (FIFO vmcnt), so earlier un-drained stores/atomics are
            // safe (strictly conservative).
            asm volatile(
                "global_load_dword   %0, %9, off\n\t"
                "global_load_dwordx4 %1, %10, off sc0\n\t"
                "global_load_dwordx4 %2, %10, off offset:16 sc0\n\t"
                "global_load_dwordx4 %3, %10, off offset:2048 sc0\n\t"
                "global_load_dwordx4 %4, %10, off offset:2064 sc0\n\t"
                "global_load_dwordx4 %5, %11, off sc0\n\t"
                "global_load_dwordx4 %6, %11, off offset:16 sc0\n\t"
                "global_load_dwordx4 %7, %11, off offset:2048 sc0\n\t"
                "global_load_dwordx4 %8, %11, off offset:2064 sc0\n\t"
                : "=&v"(xiu), "=&v"(a0), "=&v"(b0), "=&v"(a1), "=&v"(b1),
                  "=&v"(a2), "=&v"(b2), "=&v"(a3), "=&v"(b3)
                : "v"(xin), "v"(pA), "v"(pB)
                : "memory");

            float acc[16];
            #pragma unroll
            for (int i = 0; i < 16; ++i) acc[i] = 0.f;

            unsigned missing = 0u;
            asm volatile("s_waitcnt vmcnt(6)" : "+v"(a0), "+v"(b0));
            if (TAGOK(a0, b0)) { DO_CHUNK(0, a0, b0); } else missing |= 1u;
            asm volatile("s_waitcnt vmcnt(4)" : "+v"(a1), "+v"(b1));
            if (TAGOK(a1, b1)) { DO_CHUNK(1, a1, b1); } else missing |= 2u;
            asm volatile("s_waitcnt vmcnt(2)" : "+v"(a2), "+v"(b2));
            if (TAGOK(a2, b2)) { DO_CHUNK(2, a2, b2); } else missing |= 4u;
            asm volatile("s_waitcnt vmcnt(0)" : "+v"(a3), "+v"(b3), "+v"(xiu));
            if (TAGOK(a3, b3)) { DO_CHUNK(3, a3, b3); } else missing |= 8u;

            int rounds = 0;
            while (__builtin_expect(missing != 0u, 0)) {
                const bool coh = (rounds >= 24) && ((rounds & 1) != 0);
                if (missing & 1u) { poll2(pA, a0, b0, coh);
                    if (TAGOK(a0, b0)) { DO_CHUNK(0, a0, b0); missing &= ~1u; } }
                if (missing & 2u) { poll2(pA + 512, a1, b1, coh);
                    if (TAGOK(a1, b1)) { DO_CHUNK(1, a1, b1); missing &= ~2u; } }
                if (missing & 4u) { poll2(pB, a2, b2, coh);
                    if (TAGOK(a2, b2)) { DO_CHUNK(2, a2, b2); missing &= ~4u; } }
                if (missing & 8u) { poll2(pB + 512, a3, b3, coh);
                    if (TAGOK(a3, b3)) { DO_CHUNK(3, a3, b3); missing &= ~8u; } }
                if (missing) { ++rounds; if (rounds > 2) __builtin_amdgcn_s_sleep(1); }
            }

            // register butterfly; after xor 1,2,4,8 lane holds the 16-lane
            // sum of row lr; xor16/32 complete the 64-lane sum.
            {
                bool hi = lane & 1;
                #pragma unroll
                for (int i = 0; i < 8; ++i) {
                    float snd = hi ? acc[i] : acc[i + 8];
                    float kp  = hi ? acc[i + 8] : acc[i];
                    acc[i] = kp + __shfl_xor(snd, 1);
                }
                hi = lane & 2;
                #pragma unroll
                for (int i = 0; i < 4; ++i) {
                    float snd = hi ? acc[i] : acc[i + 4];
                    float kp  = hi ? acc[i + 4] : acc[i];
                    acc[i] = kp + __shfl_xor(snd, 2);
                }
                hi = lane & 4;
                #pragma unroll
                for (int i = 0; i < 2; ++i) {
                    float snd = hi ? acc[i] : acc[i + 2];
                    float kp  = hi ? acc[i + 2] : acc[i];
                    acc[i] = kp + __shfl_xor(snd, 4);
                }
                hi = lane & 8;
                {
                    float snd = hi ? acc[0] : acc[1];
                    float kp  = hi ? acc[1] : acc[0];
                    acc[0] = kp + __shfl_xor(snd, 8);
                }
                acc[0] += __shfl_xor(acc[0], 16);
                acc[0] += __shfl_xor(acc[0], 32);
            }

            // publish h_{t+1} rows (lanes 0..15 of each wave): non-returning
            // atomic swap, no sc flags -> executes at LOCAL L2 (never write-
            // combined), line dirty-resident there, visible to peers' sc0
            // polls within ~100-200 cycles.
            if (lane < 16) {
                float hvf = fast_tanh(__builtin_bit_cast(float, xi_hold) + acc[0]);
                _Float16 hf = (_Float16)hvf;
                unsigned pk = ((unsigned)(t + 1) << 16)
                            | (unsigned)__builtin_bit_cast(unsigned short, hf);
                unsigned* dst = hxl + (size_t)((t + 1) & 1) * H_DIM + myrow;
                asm volatile("global_atomic_swap %0, %1, off"
                             :: "v"(dst), "v"(pk) : "memory");
                if (xcd == 0)
                    rnn[(size_t)t * H_DIM + myrow] = hf;
            }
            xi_hold = xiu;   // xi[t+1][myrow], drained by vmcnt(0) above
        }
    } else {
        // ================= FALLBACK: global replica (round-3, validated) =====
        const int rowbase = wg * RPW;
        const int r = tid >> 5;
        const int j = tid & 31;
        half8 wreg[8];
        {
            const half8* wrow = (const half8*)(Whh + (size_t)(rowbase + r) * H_DIM);
            #pragma unroll
            for (int c = 0; c < 8; ++c) wreg[c] = wrow[j + c * 32];
        }
        if (tid < RPW) xilds[0][tid] = xi[rowbase + tid];
        __syncthreads();

        for (int t = 0; t < S_LEN; ++t) {
            float xnext = 0.f;
            if (tid < RPW && t + 1 < S_LEN)
                xnext = xi[(size_t)(t + 1) * H_DIM + rowbase + tid];

            const uint4a* p0 = (const uint4a*)(hpk + (size_t)(t & 1) * H_DIM) + tid * 2;
            const unsigned tg = (unsigned)t;
            uint4a a = {}, b = {};
            bool got0 = false, got1 = false;
            int round = 0;
            for (;;) {
                if (!got0)
                    asm volatile("global_load_dwordx4 %0, %1, off sc0 sc1"
                                 : "=v"(a) : "v"(p0) : "memory");
                if (!got1)
                    asm volatile("global_load_dwordx4 %0, %1, off sc0 sc1"
                                 : "=v"(b) : "v"(p0 + 1) : "memory");
                asm volatile("s_waitcnt vmcnt(0)" ::: "memory");
                got0 = got0 | (((a.x >> 16) == tg) & ((a.y >> 16) == tg) &
                               ((a.z >> 16) == tg) & ((a.w >> 16) == tg));
                got1 = got1 | (((b.x >> 16) == tg) & ((b.y >> 16) == tg) &
                               ((b.z >> 16) == tg) & ((b.w >> 16) == tg));
                if (got0 && got1) break;
                if (++round > 1) __builtin_amdgcn_s_sleep(1);
            }
            uint4a hp;
            hp.x = (a.x & 0xffffu) | (a.y << 16);
            hp.y = (a.z & 0xffffu) | (a.w << 16);
            hp.z = (b.x & 0xffffu) | (b.y << 16);
            hp.w = (b.z & 0xffffu) | (b.w << 16);
            *(uint4a*)&hlds[t & 1][tid * 8] = hp;
            if (tid < RPW) xilds[(t + 1) & 1][tid] = xnext;
            __syncthreads();

            float acc = 0.f;
            const _Float16* hpt = &hlds[t & 1][j * 8];
            #pragma unroll
            for (int c = 0; c < 8; ++c) {
                half8 hvv = *(const half8*)(hpt + c * 256);
                acc = dot8(wreg[c], hvv, acc);
            }
            acc += __shfl_xor(acc, 1);  acc += __shfl_xor(acc, 2);
            acc += __shfl_xor(acc, 4);  acc += __shfl_xor(acc, 8);
            acc += __shfl_xor(acc, 16);

            if (j == 0) {
                float hvf = fast_tanh(xilds[t & 1][r] + acc);
                _Float16 hf = (_Float16)hvf;
                unsigned pk = ((unsigned)(t + 1) << 16)
                            | (unsigned)__builtin_bit_cast(unsigned short, hf);
                __hip_atomic_store(&hpk[(size_t)((t + 1) & 1) * H_DIM + rowbase + r], pk,
                                   __ATOMIC_RELAXED, __HIP_MEMORY_SCOPE_AGENT);
                rnn[(size_t)t * H_DIM + rowbase + r] = hf;
            }
        }
    }
}

// ---------------- K3: head GEMM + log_softmax
__global__ __launch_bounds__(256) void head_kernel(
        const _Float16* __restrict__ rnn, const _Float16* __restrict__ Wout,
        const float* __restrict__ bout, float* __restrict__ out) {
    __shared__ __align__(16) _Float16 h8[8][H_DIM];
    __shared__ __align__(16) _Float16 wr[H_DIM];
    __shared__ float tl[8][T_TAGS];
    int tid = threadIdx.x;
    size_t sbase = (size_t)blockIdx.x * 8;
    {
        const uint4* src = (const uint4*)(rnn + sbase * H_DIM);
        uint4* dst = (uint4*)&h8[0][0];
        for (int i = tid; i < 8 * H_DIM / 8; i += 256) dst[i] = src[i];
    }
    __syncthreads();
    int sl = ((tid >> 6) << 1) | ((tid >> 5) & 1);
    int l32 = tid & 31;
    for (int t = 0; t < T_TAGS; ++t) {
        ((uint4*)wr)[tid] = ((const uint4*)(Wout + t * H_DIM))[tid];
        __syncthreads();
        float acc = 0.f;
        const _Float16* hp = &h8[sl][l32 * 64];
        const _Float16* wp = &wr[l32 * 64];
        #pragma unroll
        for (int c = 0; c < 8; ++c)
            acc = dot8(*(const half8*)(hp + c * 8), *(const half8*)(wp + c * 8), acc);
        acc += __shfl_xor(acc, 1);  acc += __shfl_xor(acc, 2);
        acc += __shfl_xor(acc, 4);  acc += __shfl_xor(acc, 8);
        acc += __shfl_xor(acc, 16);
        if (l32 == 0) tl[sl][t] = acc + bout[t];
        __syncthreads();
    }
    if (tid < 8) {
        float m = -1e30f;
        for (int t = 0; t < T_TAGS; ++t) m = fmaxf(m, tl[tid][t]);
        float sum = 0.f;
        for (int t = 0; t < T_TAGS; ++t) sum += expf(tl[tid][t] - m);
        float lse = m + logf(sum);
        for (int t = 0; t < T_TAGS; ++t) out[(sbase + tid) * T_TAGS + t] = tl[tid][t] - lse;
    }
}

extern "C" void kernel_launch(void* const* d_in, const int* in_sizes, int n_in,
                              void* d_out, int out_size, void* d_ws, size_t ws_size,
                              hipStream_t stream) {
    const int*   sent = (const int*)  d_in[0];
    const float* emb  = (const float*)d_in[1];
    const float* wih  = (const float*)d_in[2];
    const float* whh  = (const float*)d_in[3];
    const float* bih  = (const float*)d_in[4];
    const float* bhh  = (const float*)d_in[5];
    const float* wout = (const float*)d_in[6];
    const float* bout = (const float*)d_in[7];
    const float* h0   = (const float*)d_in[8];

    char* ws = (char*)d_ws;
    _Float16*       whh_h  = (_Float16*)      (ws + 0);           //  8 MB
    unsigned short* wih_b  = (unsigned short*)(ws + 8388608);     //  4 MB
    _Float16*       wout_h = (_Float16*)      (ws + 12582912);    //  256 KB
    unsigned short* X_b    = (unsigned short*)(ws + 12845056);    //  16 MB
    unsigned*       hx     = (unsigned*)      (ws + 13000704);    //  128 KB, aliases X_b (dead after xi_gemm)
    unsigned*       hpk    = (unsigned*)      (ws + 29605888);    //  16 KB, aliases X_b tail
    float*          xi     = (float*)         (ws + 29622272);    //  64 MB
    _Float16*       rnn    = (_Float16*)      (ws + 96731136);    //  32 MB
    unsigned*       ctl    = (unsigned*)      (ws + 130285568);   //  64 B election counters

    hipMemsetAsync(ctl, 0, 64, stream);
    {
        const int total = H_DIM * H_DIM + H_DIM * E_DIM + 64 * H_DIM;
        cast_kernel<<<(total + 255) / 256, 256, 0, stream>>>(
            whh, wih, wout, whh_h, wih_b, wout_h);
    }
    embed_kernel<<<(S_LEN * E_DIM) / 256, 256, 0, stream>>>(sent, emb, X_b);
    xi_gemm<<<dim3(H_DIM / 16, S_LEN / 64), 256, 0, stream>>>(X_b, wih_b, bih, bhh, xi);
    init_hpk<<<H_DIM / 256, 256, 0, stream>>>(h0, hpk, hx);
    rnn_seq<<<NWG, 256, 0, stream>>>(whh_h, xi, hpk, hx, ctl, rnn);
    head_kernel<<<S_LEN / 8, 256, 0, stream>>>(rnn, wout_h, bout, (float*)d_out);
}

// Round 4
// 51700.250 us; speedup vs baseline: 3.8630x; 3.8630x over previous
//
#include <hip/hip_runtime.h>
#include <hip/hip_bf16.h>

#define S_LEN 8192
#define E_DIM 1024
#define H_DIM 2048
#define T_TAGS 50
#define NWG 256            // persistent workgroups for the recurrence
#define RPW (H_DIM / NWG)  // fallback path: 8 rows per WG

typedef short short8 __attribute__((ext_vector_type(8)));
typedef float floatx4 __attribute__((ext_vector_type(4)));
typedef _Float16 half8 __attribute__((ext_vector_type(8)));
typedef _Float16 half2v __attribute__((ext_vector_type(2)));
typedef unsigned int uint4a __attribute__((ext_vector_type(4)));

__device__ __forceinline__ unsigned short f2bf(float f) {
    unsigned u = __builtin_bit_cast(unsigned, f);
    unsigned r = (u + 0x7fffu + ((u >> 16) & 1u)) >> 16;
    return (unsigned short)r;
}

__device__ __forceinline__ float dot8(half8 a, half8 b, float acc) {
#if __has_builtin(__builtin_amdgcn_fdot2)
    union U { half8 v; half2v p[4]; };
    U ua; ua.v = a; U ub; ub.v = b;
    acc = __builtin_amdgcn_fdot2(ua.p[0], ub.p[0], acc, false);
    acc = __builtin_amdgcn_fdot2(ua.p[1], ub.p[1], acc, false);
    acc = __builtin_amdgcn_fdot2(ua.p[2], ub.p[2], acc, false);
    acc = __builtin_amdgcn_fdot2(ua.p[3], ub.p[3], acc, false);
#else
    #pragma unroll
    for (int i = 0; i < 8; ++i) acc += (float)a[i] * (float)b[i];
#endif
    return acc;
}

__device__ __forceinline__ float fast_tanh(float x) {
    float xc = fminf(fmaxf(x, -9.f), 9.f);
    float e = __expf(2.f * xc);
    return (e - 1.f) / (e + 1.f);
}

// Straggler re-poll of one 8-word tagged chunk (2x dwordx4).
// PROTOCOL (validated R0, restored after R2/R3 falsified alternatives):
//   fast rounds: sc0 nt  — the nt hint is LOAD-BEARING: bare sc0 loads can be
//     serviced from a stale clean line (R2/R3: ~24us/step eviction-timescale
//     stalls); nt forces a re-read of the coherent copy.
//   escalation (rounds>=24): sc0 sc1 — IF-scope truth; publishes are sc0 sc1
//     write-through so IF provably has the value -> progress guaranteed.
// NOTE gfx950 assembler: offset: immediate must PRECEDE cache flags.
__device__ __forceinline__ void poll2(const unsigned* p, uint4a& a, uint4a& b, bool coh) {
    if (coh)
        asm volatile("global_load_dwordx4 %0, %2, off sc0 sc1\n\t"
                     "global_load_dwordx4 %1, %2, off offset:16 sc0 sc1\n\t"
                     "s_waitcnt vmcnt(0)"
                     : "=&v"(a), "=&v"(b) : "v"(p) : "memory");
    else
        asm volatile("global_load_dwordx4 %0, %2, off sc0 nt\n\t"
                     "global_load_dwordx4 %1, %2, off offset:16 sc0 nt\n\t"
                     "s_waitcnt vmcnt(0)"
                     : "=&v"(a), "=&v"(b) : "v"(p) : "memory");
}

#define TAGOK(A, B)                                                          \
    (((A.x >> 16) == tg) & ((A.y >> 16) == tg) & ((A.z >> 16) == tg) &       \
     ((A.w >> 16) == tg) & ((B.x >> 16) == tg) & ((B.y >> 16) == tg) &       \
     ((B.z >> 16) == tg) & ((B.w >> 16) == tg))

// Strip tags, rebuild half8, accumulate 16 row-partials for column chunk J.
#define DO_CHUNK(J, A, B)                                                    \
    do {                                                                     \
        unsigned u0 = (A.x & 0xffffu) | (A.y << 16);                         \
        unsigned u1 = (A.z & 0xffffu) | (A.w << 16);                         \
        unsigned u2 = (B.x & 0xffffu) | (B.y << 16);                         \
        unsigned u3 = (B.z & 0xffffu) | (B.w << 16);                         \
        uint4a hp; hp.x = u0; hp.y = u1; hp.z = u2; hp.w = u3;               \
        half8 hv = __builtin_bit_cast(half8, hp);                            \
        _Pragma("unroll")                                                    \
        for (int i_ = 0; i_ < 16; ++i_) acc[i_] = dot8(w[i_][J], hv, acc[i_]); \
    } while (0)

// ---------------- K0a: cast weights (W_hh->f16, W_ih->bf16, W_out->f16 padded)
__global__ __launch_bounds__(256) void cast_kernel(
        const float* __restrict__ whh, const float* __restrict__ wih,
        const float* __restrict__ wout,
        _Float16* __restrict__ whh_h, unsigned short* __restrict__ wih_b,
        _Float16* __restrict__ wout_h) {
    const int nWhh = H_DIM * H_DIM;
    const int nWih = H_DIM * E_DIM;
    const int nWout = 64 * H_DIM;
    long long i = (long long)blockIdx.x * 256 + threadIdx.x;
    if (i < nWhh) { whh_h[i] = (_Float16)whh[i]; return; }
    i -= nWhh;
    if (i < nWih) { wih_b[i] = f2bf(wih[i]); return; }
    i -= nWih;
    if (i < nWout) {
        int r = (int)(i >> 11), c = (int)(i & 2047);
        wout_h[i] = (r < T_TAGS) ? (_Float16)wout[r * H_DIM + c] : (_Float16)0.f;
    }
}

// ---------------- K0b: embedding gather -> bf16 X
__global__ __launch_bounds__(256) void embed_kernel(
        const int* __restrict__ sent, const float* __restrict__ emb,
        unsigned short* __restrict__ Xb) {
    size_t i = (size_t)blockIdx.x * 256 + threadIdx.x;
    size_t s = i >> 10, e = i & 1023;
    Xb[i] = f2bf(emb[(size_t)sent[s] * E_DIM + e]);
}

// ---------------- K1: xi = X @ W_ih^T + b_ih + b_hh   (bf16 MFMA)
__global__ __launch_bounds__(256) void xi_gemm(
        const unsigned short* __restrict__ Xb, const unsigned short* __restrict__ Wb,
        const float* __restrict__ bih, const float* __restrict__ bhh,
        float* __restrict__ xi) {
    int lane = threadIdx.x & 63;
    int w = threadIdx.x >> 6;
    int m0 = blockIdx.y * 64 + w * 16;
    int n0 = blockIdx.x * 16;
    int mi = m0 + (lane & 15);
    int ni = n0 + (lane & 15);
    int q8 = (lane >> 4) * 8;
    const short8* arow = (const short8*)(Xb + (size_t)mi * E_DIM + q8);
    const short8* brow = (const short8*)(Wb + (size_t)ni * E_DIM + q8);
    floatx4 acc = {0.f, 0.f, 0.f, 0.f};
    #pragma unroll 4
    for (int k = 0; k < E_DIM / 32; ++k) {
        short8 a = arow[k * 4];
        short8 b = brow[k * 4];
        acc = __builtin_amdgcn_mfma_f32_16x16x32_bf16(a, b, acc, 0, 0, 0);
    }
    float bias = bih[ni] + bhh[ni];
    int rbase = (lane >> 4) * 4;
    #pragma unroll
    for (int i = 0; i < 4; ++i) {
        xi[(size_t)(m0 + rbase + i) * H_DIM + ni] = acc[i] + bias;
    }
}

// ---------------- K1b: init tagged h buffers: global hpk (fallback) + 8 per-XCD
// replicas hx (fast). buf0 = (h0, tag 0); buf1 = never-matching tag.
__global__ __launch_bounds__(256) void init_hpk(
        const float* __restrict__ h0, unsigned* __restrict__ hpk,
        unsigned* __restrict__ hx) {
    int i = blockIdx.x * 256 + threadIdx.x;   // grid covers H_DIM
    if (i < H_DIM) {
        unsigned short hb = __builtin_bit_cast(unsigned short, (_Float16)h0[i]);
        unsigned pk = (unsigned)hb;           // tag 0 in high 16 bits
        hpk[i] = pk;
        hpk[H_DIM + i] = 0xFFFF0000u;
        #pragma unroll
        for (int x = 0; x < 8; ++x) {
            hx[(size_t)x * 2 * H_DIM + i] = pk;
            hx[(size_t)x * 2 * H_DIM + H_DIM + i] = 0xFFFF0000u;
        }
    }
}

// ---------------- K2: persistent sequential recurrence.
// FAST PATH (placement uniform: 32 WGs on every XCD): each XCD runs a full
// independent replica.
// PROTOCOL HISTORY (all measured):
//   R0 (validated, 3.16us/step): publish store sc0 sc1 (write-through, updates
//       local L2 en route to IF); poll sc0 nt, escalate sc0 sc1 at >=24.
//   R2 (24us/step): publish sc0-only + poll bare-sc0 -> WRITE 33MB proves the
//       publish stayed dirty in local L2, but bare-sc0 polls read stale clean
//       lines until eviction; sc1 escalation reads IF which never got the data.
//   R3 (24us/step): atomic publish -> WRITE 557MB proves gfx950 atomics
//       execute MEMORY-SIDE (at IF), invalidating local L2 (FETCH 1.04GB);
//       bare-sc0 polls still stall on stale lines.
// => THIS ROUND: R0 protocol restored verbatim. Structural changes kept:
//   * NO LDS staging, NO __syncthreads in the step loop; per-WAVE polls of the
//     full 2048-word h as four 8-word tagged chunks/lane, staged vmcnt
//     (6/4/2/0) so chunk-j FMAs overlap chunks j+1..3 in flight. Tag chain
//     carries buffer-overwrite safety (each wave validates the FULL h before
//     publishing, so a tag t+1 publish proves every wave consumed tag t-1).
//   * xi via register prefetch one step ahead, drained by vmcnt(0).
// FALLBACK (placement skew): round-3 global protocol, UNCHANGED (validated).
__global__ __launch_bounds__(256, 1) void rnn_seq(
        const _Float16* __restrict__ Whh, const float* __restrict__ xi,
        unsigned* __restrict__ hpk, unsigned* __restrict__ hx,
        unsigned* __restrict__ ctl, _Float16* __restrict__ rnn) {
    __shared__ __align__(16) _Float16 hlds[2][H_DIM];     // fallback only
    __shared__ float xilds[2][64];                        // fallback only
    __shared__ int sh_xcd, sh_rank, sh_fast;
    const int tid = threadIdx.x;
    const int wg = blockIdx.x;

    // ---- one-time election: discover XCD, rank within XCD, uniformity.
    // Bounded: grid=256 at 1 WG/CU on 256 CUs is co-resident (r1-r3 property),
    // and every WG increments ctl[8] exactly once -> the spin terminates.
    if (tid == 0) {
        unsigned x;
        asm volatile("s_getreg_b32 %0, hwreg(HW_REG_XCC_ID)" : "=s"(x));
        x &= 7u;
        unsigned rk = __hip_atomic_fetch_add(&ctl[x], 1u, __ATOMIC_RELAXED,
                                             __HIP_MEMORY_SCOPE_AGENT);
        __hip_atomic_fetch_add(&ctl[8], 1u, __ATOMIC_RELEASE,
                               __HIP_MEMORY_SCOPE_AGENT);
        while (__hip_atomic_load(&ctl[8], __ATOMIC_ACQUIRE,
                                 __HIP_MEMORY_SCOPE_AGENT) < (unsigned)NWG)
            __builtin_amdgcn_s_sleep(2);
        int fast = 1;
        for (int k = 0; k < 8; ++k)
            fast &= (__hip_atomic_load(&ctl[k], __ATOMIC_RELAXED,
                                       __HIP_MEMORY_SCOPE_AGENT) == 32u);
        sh_xcd = (int)x; sh_rank = (int)rk; sh_fast = fast;
    }
    __syncthreads();
    const int xcd = sh_xcd, rank = sh_rank, use_fast = sh_fast;

    if (use_fast && rank < 32) {
        // ================= FAST PATH: per-XCD replica =================
        const int lane = tid & 63;
        const int wv = tid >> 6;           // wave 0..3
        const int wgrow = rank * 64;       // this WG's 64 rows
        unsigned* hxl = hx + (size_t)xcd * 2 * H_DIM;   // local replica buffer

        // weights -> VGPRs: thread(wv,lane) holds rows wgrow+wv*16+i (i<16),
        // cols lane*8 + j*512 .. +8 (j<4). 256 VGPRs of weights.
        half8 w[16][4];
        {
            const _Float16* wb = Whh + (size_t)(wgrow + wv * 16) * H_DIM + lane * 8;
            #pragma unroll
            for (int i = 0; i < 16; ++i) {
                const half8* rp = (const half8*)(wb + (size_t)i * H_DIM);
                #pragma unroll
                for (int j = 0; j < 4; ++j) w[i][j] = rp[j * 64];
            }
        }

        // bit-reversed row owned by the butterfly's publishing lane (lane<16)
        const int lr = ((lane & 1) << 3) | (((lane >> 1) & 1) << 2) |
                       (((lane >> 2) & 1) << 1) | ((lane >> 3) & 1);
        const int myrow = wgrow + wv * 16 + lr;          // row published by this lane
        const float* xip = xi + myrow;
        unsigned xi_hold = __builtin_bit_cast(unsigned, xip[0]);   // xi[0][myrow]

        for (int t = 0; t < S_LEN; ++t) {
            const unsigned tg = (unsigned)t;
            const unsigned* pA = hxl + (size_t)(t & 1) * H_DIM + lane * 8;
            const unsigned* pB = pA + 1024;   // +4096 B: chunks j=2,3
            const float* xin = xip + (size_t)(t + 1 < S_LEN ? t + 1 : t) * H_DIM;
            unsigned xiu;
            uint4a a0, b0, a1, b1, a2, b2, a3, b3;
            // Issue xi[t+1] prefetch + all 4 chunk-pair polls in fixed order.
            // vmcnt staging below relies only on "all but last N issued are
            // complete" (FIFO vmcnt), so earlier un-drained stores are safe
            // (strictly conservative).
            asm volatile(
                "global_load_dword   %0, %9, off\n\t"
                "global_load_dwordx4 %1, %10, off sc0 nt\n\t"
                "global_load_dwordx4 %2, %10, off offset:16 sc0 nt\n\t"
                "global_load_dwordx4 %3, %10, off offset:2048 sc0 nt\n\t"
                "global_load_dwordx4 %4, %10, off offset:2064 sc0 nt\n\t"
                "global_load_dwordx4 %5, %11, off sc0 nt\n\t"
                "global_load_dwordx4 %6, %11, off offset:16 sc0 nt\n\t"
                "global_load_dwordx4 %7, %11, off offset:2048 sc0 nt\n\t"
                "global_load_dwordx4 %8, %11, off offset:2064 sc0 nt\n\t"
                : "=&v"(xiu), "=&v"(a0), "=&v"(b0), "=&v"(a1), "=&v"(b1),
                  "=&v"(a2), "=&v"(b2), "=&v"(a3), "=&v"(b3)
                : "v"(xin), "v"(pA), "v"(pB)
                : "memory");

            float acc[16];
            #pragma unroll
            for (int i = 0; i < 16; ++i) acc[i] = 0.f;

            unsigned missing = 0u;
            asm volatile("s_waitcnt vmcnt(6)" : "+v"(a0), "+v"(b0));
            if (TAGOK(a0, b0)) { DO_CHUNK(0, a0, b0); } else missing |= 1u;
            asm volatile("s_waitcnt vmcnt(4)" : "+v"(a1), "+v"(b1));
            if (TAGOK(a1, b1)) { DO_CHUNK(1, a1, b1); } else missing |= 2u;
            asm volatile("s_waitcnt vmcnt(2)" : "+v"(a2), "+v"(b2));
            if (TAGOK(a2, b2)) { DO_CHUNK(2, a2, b2); } else missing |= 4u;
            asm volatile("s_waitcnt vmcnt(0)" : "+v"(a3), "+v"(b3), "+v"(xiu));
            if (TAGOK(a3, b3)) { DO_CHUNK(3, a3, b3); } else missing |= 8u;

            int rounds = 0;
            while (__builtin_expect(missing != 0u, 0)) {
                const bool coh = (rounds >= 24);
                if (missing & 1u) { poll2(pA, a0, b0, coh);
                    if (TAGOK(a0, b0)) { DO_CHUNK(0, a0, b0); missing &= ~1u; } }
                if (missing & 2u) { poll2(pA + 512, a1, b1, coh);
                    if (TAGOK(a1, b1)) { DO_CHUNK(1, a1, b1); missing &= ~2u; } }
                if (missing & 4u) { poll2(pB, a2, b2, coh);
                    if (TAGOK(a2, b2)) { DO_CHUNK(2, a2, b2); missing &= ~4u; } }
                if (missing & 8u) { poll2(pB + 512, a3, b3, coh);
                    if (TAGOK(a3, b3)) { DO_CHUNK(3, a3, b3); missing &= ~8u; } }
                if (missing) { ++rounds; if (rounds > 2) __builtin_amdgcn_s_sleep(1); }
            }

            // register butterfly; after xor 1,2,4,8 lane holds the 16-lane
            // sum of row lr; xor16/32 complete the 64-lane sum.
            {
                bool hi = lane & 1;
                #pragma unroll
                for (int i = 0; i < 8; ++i) {
                    float snd = hi ? acc[i] : acc[i + 8];
                    float kp  = hi ? acc[i + 8] : acc[i];
                    acc[i] = kp + __shfl_xor(snd, 1);
                }
                hi = lane & 2;
                #pragma unroll
                for (int i = 0; i < 4; ++i) {
                    float snd = hi ? acc[i] : acc[i + 4];
                    float kp  = hi ? acc[i + 4] : acc[i];
                    acc[i] = kp + __shfl_xor(snd, 2);
                }
                hi = lane & 4;
                #pragma unroll
                for (int i = 0; i < 2; ++i) {
                    float snd = hi ? acc[i] : acc[i + 2];
                    float kp  = hi ? acc[i + 2] : acc[i];
                    acc[i] = kp + __shfl_xor(snd, 4);
                }
                hi = lane & 8;
                {
                    float snd = hi ? acc[0] : acc[1];
                    float kp  = hi ? acc[1] : acc[0];
                    acc[0] = kp + __shfl_xor(snd, 8);
                }
                acc[0] += __shfl_xor(acc[0], 16);
                acc[0] += __shfl_xor(acc[0], 32);
            }

            // publish h_{t+1} rows (lanes 0..15 of each wave) — validated R0
            // protocol: sc0 sc1 write-through (updates local L2 en route,
            // reaches IF -> escalated polls provably terminate).
            if (lane < 16) {
                float hvf = fast_tanh(__builtin_bit_cast(float, xi_hold) + acc[0]);
                _Float16 hf = (_Float16)hvf;
                unsigned pk = ((unsigned)(t + 1) << 16)
                            | (unsigned)__builtin_bit_cast(unsigned short, hf);
                unsigned* dst = hxl + (size_t)((t + 1) & 1) * H_DIM + myrow;
                asm volatile("global_store_dword %0, %1, off sc0 sc1"
                             :: "v"(dst), "v"(pk) : "memory");
                if (xcd == 0)
                    rnn[(size_t)t * H_DIM + myrow] = hf;
            }
            xi_hold = xiu;   // xi[t+1][myrow], drained by vmcnt(0) above
        }
    } else {
        // ================= FALLBACK: global replica (round-3, validated) =====
        const int rowbase = wg * RPW;
        const int r = tid >> 5;
        const int j = tid & 31;
        half8 wreg[8];
        {
            const half8* wrow = (const half8*)(Whh + (size_t)(rowbase + r) * H_DIM);
            #pragma unroll
            for (int c = 0; c < 8; ++c) wreg[c] = wrow[j + c * 32];
        }
        if (tid < RPW) xilds[0][tid] = xi[rowbase + tid];
        __syncthreads();

        for (int t = 0; t < S_LEN; ++t) {
            float xnext = 0.f;
            if (tid < RPW && t + 1 < S_LEN)
                xnext = xi[(size_t)(t + 1) * H_DIM + rowbase + tid];

            const uint4a* p0 = (const uint4a*)(hpk + (size_t)(t & 1) * H_DIM) + tid * 2;
            const unsigned tg = (unsigned)t;
            uint4a a = {}, b = {};
            bool got0 = false, got1 = false;
            int round = 0;
            for (;;) {
                if (!got0)
                    asm volatile("global_load_dwordx4 %0, %1, off sc0 sc1"
                                 : "=v"(a) : "v"(p0) : "memory");
                if (!got1)
                    asm volatile("global_load_dwordx4 %0, %1, off sc0 sc1"
                                 : "=v"(b) : "v"(p0 + 1) : "memory");
                asm volatile("s_waitcnt vmcnt(0)" ::: "memory");
                got0 = got0 | (((a.x >> 16) == tg) & ((a.y >> 16) == tg) &
                               ((a.z >> 16) == tg) & ((a.w >> 16) == tg));
                got1 = got1 | (((b.x >> 16) == tg) & ((b.y >> 16) == tg) &
                               ((b.z >> 16) == tg) & ((b.w >> 16) == tg));
                if (got0 && got1) break;
                if (++round > 1) __builtin_amdgcn_s_sleep(1);
            }
            uint4a hp;
            hp.x = (a.x & 0xffffu) | (a.y << 16);
            hp.y = (a.z & 0xffffu) | (a.w << 16);
            hp.z = (b.x & 0xffffu) | (b.y << 16);
            hp.w = (b.z & 0xffffu) | (b.w << 16);
            *(uint4a*)&hlds[t & 1][tid * 8] = hp;
            if (tid < RPW) xilds[(t + 1) & 1][tid] = xnext;
            __syncthreads();

            float acc = 0.f;
            const _Float16* hpt = &hlds[t & 1][j * 8];
            #pragma unroll
            for (int c = 0; c < 8; ++c) {
                half8 hvv = *(const half8*)(hpt + c * 256);
                acc = dot8(wreg[c], hvv, acc);
            }
            acc += __shfl_xor(acc, 1);  acc += __shfl_xor(acc, 2);
            acc += __shfl_xor(acc, 4);  acc += __shfl_xor(acc, 8);
            acc += __shfl_xor(acc, 16);

            if (j == 0) {
                float hvf = fast_tanh(xilds[t & 1][r] + acc);
                _Float16 hf = (_Float16)hvf;
                unsigned pk = ((unsigned)(t + 1) << 16)
                            | (unsigned)__builtin_bit_cast(unsigned short, hf);
                __hip_atomic_store(&hpk[(size_t)((t + 1) & 1) * H_DIM + rowbase + r], pk,
                                   __ATOMIC_RELAXED, __HIP_MEMORY_SCOPE_AGENT);
                rnn[(size_t)t * H_DIM + rowbase + r] = hf;
            }
        }
    }
}

// ---------------- K3: head GEMM + log_softmax
__global__ __launch_bounds__(256) void head_kernel(
        const _Float16* __restrict__ rnn, const _Float16* __restrict__ Wout,
        const float* __restrict__ bout, float* __restrict__ out) {
    __shared__ __align__(16) _Float16 h8[8][H_DIM];
    __shared__ __align__(16) _Float16 wr[H_DIM];
    __shared__ float tl[8][T_TAGS];
    int tid = threadIdx.x;
    size_t sbase = (size_t)blockIdx.x * 8;
    {
        const uint4* src = (const uint4*)(rnn + sbase * H_DIM);
        uint4* dst = (uint4*)&h8[0][0];
        for (int i = tid; i < 8 * H_DIM / 8; i += 256) dst[i] = src[i];
    }
    __syncthreads();
    int sl = ((tid >> 6) << 1) | ((tid >> 5) & 1);
    int l32 = tid & 31;
    for (int t = 0; t < T_TAGS; ++t) {
        ((uint4*)wr)[tid] = ((const uint4*)(Wout + t * H_DIM))[tid];
        __syncthreads();
        float acc = 0.f;
        const _Float16* hp = &h8[sl][l32 * 64];
        const _Float16* wp = &wr[l32 * 64];
        #pragma unroll
        for (int c = 0; c < 8; ++c)
            acc = dot8(*(const half8*)(hp + c * 8), *(const half8*)(wp + c * 8), acc);
        acc += __shfl_xor(acc, 1);  acc += __shfl_xor(acc, 2);
        acc += __shfl_xor(acc, 4);  acc += __shfl_xor(acc, 8);
        acc += __shfl_xor(acc, 16);
        if (l32 == 0) tl[sl][t] = acc + bout[t];
        __syncthreads();
    }
    if (tid < 8) {
        float m = -1e30f;
        for (int t = 0; t < T_TAGS; ++t) m = fmaxf(m, tl[tid][t]);
        float sum = 0.f;
        for (int t = 0; t < T_TAGS; ++t) sum += expf(tl[tid][t] - m);
        float lse = m + logf(sum);
        for (int t = 0; t < T_TAGS; ++t) out[(sbase + tid) * T_TAGS + t] = tl[tid][t] - lse;
    }
}

extern "C" void kernel_launch(void* const* d_in, const int* in_sizes, int n_in,
                              void* d_out, int out_size, void* d_ws, size_t ws_size,
                              hipStream_t stream) {
    const int*   sent = (const int*)  d_in[0];
    const float* emb  = (const float*)d_in[1];
    const float* wih  = (const float*)d_in[2];
    const float* whh  = (const float*)d_in[3];
    const float* bih  = (const float*)d_in[4];
    const float* bhh  = (const float*)d_in[5];
    const float* wout = (const float*)d_in[6];
    const float* bout = (const float*)d_in[7];
    const float* h0   = (const float*)d_in[8];

    char* ws = (char*)d_ws;
    _Float16*       whh_h  = (_Float16*)      (ws + 0);           //  8 MB
    unsigned short* wih_b  = (unsigned short*)(ws + 8388608);     //  4 MB
    _Float16*       wout_h = (_Float16*)      (ws + 12582912);    //  256 KB
    unsigned short* X_b    = (unsigned short*)(ws + 12845056);    //  16 MB
    unsigned*       hx     = (unsigned*)      (ws + 13000704);    //  128 KB, aliases X_b (dead after xi_gemm)
    unsigned*       hpk    = (unsigned*)      (ws + 29605888);    //  16 KB, aliases X_b tail
    float*          xi     = (float*)         (ws + 29622272);    //  64 MB
    _Float16*       rnn    = (_Float16*)      (ws + 96731136);    //  32 MB
    unsigned*       ctl    = (unsigned*)      (ws + 130285568);   //  64 B election counters

    hipMemsetAsync(ctl, 0, 64, stream);
    {
        const int total = H_DIM * H_DIM + H_DIM * E_DIM + 64 * H_DIM;
        cast_kernel<<<(total + 255) / 256, 256, 0, stream>>>(
            whh, wih, wout, whh_h, wih_b, wout_h);
    }
    embed_kernel<<<(S_LEN * E_DIM) / 256, 256, 0, stream>>>(sent, emb, X_b);
    xi_gemm<<<dim3(H_DIM / 16, S_LEN / 64), 256, 0, stream>>>(X_b, wih_b, bih, bhh, xi);
    init_hpk<<<H_DIM / 256, 256, 0, stream>>>(h0, hpk, hx);
    rnn_seq<<<NWG, 256, 0, stream>>>(whh_h, xi, hpk, hx, ctl, rnn);
    head_kernel<<<S_LEN / 8, 256, 0, stream>>>(rnn, wout_h, bout, (float*)d_out);
}

// Round 7
// 27099.826 us; speedup vs baseline: 7.3697x; 1.9078x over previous
//
#include <hip/hip_runtime.h>
#include <hip/hip_bf16.h>

#define S_LEN 8192
#define E_DIM 1024
#define H_DIM 2048
#define T_TAGS 50
#define NWG 256            // persistent workgroups for the recurrence
#define RPW (H_DIM / NWG)  // fallback path: 8 rows per WG

typedef short short8 __attribute__((ext_vector_type(8)));
typedef float floatx4 __attribute__((ext_vector_type(4)));
typedef _Float16 half8 __attribute__((ext_vector_type(8)));
typedef _Float16 half2v __attribute__((ext_vector_type(2)));
typedef unsigned int uint4a __attribute__((ext_vector_type(4)));

__device__ __forceinline__ unsigned short f2bf(float f) {
    unsigned u = __builtin_bit_cast(unsigned, f);
    unsigned r = (u + 0x7fffu + ((u >> 16) & 1u)) >> 16;
    return (unsigned short)r;
}

__device__ __forceinline__ float dot8(half8 a, half8 b, float acc) {
#if __has_builtin(__builtin_amdgcn_fdot2)
    union U { half8 v; half2v p[4]; };
    U ua; ua.v = a; U ub; ub.v = b;
    acc = __builtin_amdgcn_fdot2(ua.p[0], ub.p[0], acc, false);
    acc = __builtin_amdgcn_fdot2(ua.p[1], ub.p[1], acc, false);
    acc = __builtin_amdgcn_fdot2(ua.p[2], ub.p[2], acc, false);
    acc = __builtin_amdgcn_fdot2(ua.p[3], ub.p[3], acc, false);
#else
    #pragma unroll
    for (int i = 0; i < 8; ++i) acc += (float)a[i] * (float)b[i];
#endif
    return acc;
}

__device__ __forceinline__ float fast_tanh(float x) {
    float xc = fminf(fmaxf(x, -9.f), 9.f);
    float e = __expf(2.f * xc);
    return (e - 1.f) / (e + 1.f);
}

#define TAGOK(A, B)                                                          \
    (((A.x >> 16) == tg) & ((A.y >> 16) == tg) & ((A.z >> 16) == tg) &       \
     ((A.w >> 16) == tg) & ((B.x >> 16) == tg) & ((B.y >> 16) == tg) &       \
     ((B.z >> 16) == tg) & ((B.w >> 16) == tg))

// ---------------- K0a: cast weights (W_hh->f16, W_ih->bf16, W_out->f16 padded)
__global__ __launch_bounds__(256) void cast_kernel(
        const float* __restrict__ whh, const float* __restrict__ wih,
        const float* __restrict__ wout,
        _Float16* __restrict__ whh_h, unsigned short* __restrict__ wih_b,
        _Float16* __restrict__ wout_h) {
    const int nWhh = H_DIM * H_DIM;
    const int nWih = H_DIM * E_DIM;
    const int nWout = 64 * H_DIM;
    long long i = (long long)blockIdx.x * 256 + threadIdx.x;
    if (i < nWhh) { whh_h[i] = (_Float16)whh[i]; return; }
    i -= nWhh;
    if (i < nWih) { wih_b[i] = f2bf(wih[i]); return; }
    i -= nWih;
    if (i < nWout) {
        int r = (int)(i >> 11), c = (int)(i & 2047);
        wout_h[i] = (r < T_TAGS) ? (_Float16)wout[r * H_DIM + c] : (_Float16)0.f;
    }
}

// ---------------- K0b: embedding gather -> bf16 X
__global__ __launch_bounds__(256) void embed_kernel(
        const int* __restrict__ sent, const float* __restrict__ emb,
        unsigned short* __restrict__ Xb) {
    size_t i = (size_t)blockIdx.x * 256 + threadIdx.x;
    size_t s = i >> 10, e = i & 1023;
    Xb[i] = f2bf(emb[(size_t)sent[s] * E_DIM + e]);
}

// ---------------- K1: xi = X @ W_ih^T + b_ih + b_hh   (bf16 MFMA)
__global__ __launch_bounds__(256) void xi_gemm(
        const unsigned short* __restrict__ Xb, const unsigned short* __restrict__ Wb,
        const float* __restrict__ bih, const float* __restrict__ bhh,
        float* __restrict__ xi) {
    int lane = threadIdx.x & 63;
    int w = threadIdx.x >> 6;
    int m0 = blockIdx.y * 64 + w * 16;
    int n0 = blockIdx.x * 16;
    int mi = m0 + (lane & 15);
    int ni = n0 + (lane & 15);
    int q8 = (lane >> 4) * 8;
    const short8* arow = (const short8*)(Xb + (size_t)mi * E_DIM + q8);
    const short8* brow = (const short8*)(Wb + (size_t)ni * E_DIM + q8);
    floatx4 acc = {0.f, 0.f, 0.f, 0.f};
    #pragma unroll 4
    for (int k = 0; k < E_DIM / 32; ++k) {
        short8 a = arow[k * 4];
        short8 b = brow[k * 4];
        acc = __builtin_amdgcn_mfma_f32_16x16x32_bf16(a, b, acc, 0, 0, 0);
    }
    float bias = bih[ni] + bhh[ni];
    int rbase = (lane >> 4) * 4;
    #pragma unroll
    for (int i = 0; i < 4; ++i) {
        xi[(size_t)(m0 + rbase + i) * H_DIM + ni] = acc[i] + bias;
    }
}

// ---------------- K1b: init tagged h buffers: global hpk (fallback) + 8 per-XCD
// replicas hx (fast). buf0 = (h0, tag 0); buf1 = never-matching tag.
__global__ __launch_bounds__(256) void init_hpk(
        const float* __restrict__ h0, unsigned* __restrict__ hpk,
        unsigned* __restrict__ hx) {
    int i = blockIdx.x * 256 + threadIdx.x;   // grid covers H_DIM
    if (i < H_DIM) {
        unsigned short hb = __builtin_bit_cast(unsigned short, (_Float16)h0[i]);
        unsigned pk = (unsigned)hb;           // tag 0 in high 16 bits
        hpk[i] = pk;
        hpk[H_DIM + i] = 0xFFFF0000u;
        #pragma unroll
        for (int x = 0; x < 8; ++x) {
            hx[(size_t)x * 2 * H_DIM + i] = pk;
            hx[(size_t)x * 2 * H_DIM + H_DIM + i] = 0xFFFF0000u;
        }
    }
}

// ---------------- K2: persistent sequential recurrence.
// FAST PATH = the validated R0 structure (3.16us/step measured): per-thread
// 32B tagged poll (sc0 nt, escalate sc0 sc1 at >=24 rounds), LDS staging of h,
// ONE barrier/step, publish via sc0 sc1 write-through store.
// SINGLE change vs R0: W_hh rows -> registers via SELF-CONTAINED inline-asm
// blocks (4 loads + s_waitcnt vmcnt(0) inside ONE asm). R6's split form
// (separate loads, later drain) let the register allocator spill the
// NOT-YET-ARRIVED registers to scratch -> garbage (absmax 1.47). With the
// wait inside, outputs are architecturally valid when the compiler regains
// control, so spills (if any) copy correct data. Asm outputs cannot be
// re-materialized from memory, so the per-step 256 KB/CU W_hh re-stream
// (R0's dominant cost: ~4700 cyc ~= 1.95us of the 3.16us step, inferred from
// VGPR_Count=152 proving non-residency) is eliminated.
// PROTOCOL HISTORY (measured): R0 ok; R2 sc0-only store = store-buffer limbo
// (24us/step); R3 atomic = memory-side at IF, L2 invalidated (24us/step);
// R4 barrier-free per-wave polls = serialized straggler drains (5.9us/step).
// FALLBACK (placement skew): global protocol, UNCHANGED (validated).
__global__ __launch_bounds__(256, 1) void rnn_seq(
        const _Float16* __restrict__ Whh, const float* __restrict__ xi,
        unsigned* __restrict__ hpk, unsigned* __restrict__ hx,
        unsigned* __restrict__ ctl, _Float16* __restrict__ rnn) {
    __shared__ __align__(16) _Float16 hlds[2][H_DIM];     // 8 KB double buffer
    __shared__ float xilds[2][64];
    __shared__ int sh_xcd, sh_rank, sh_fast;
    const int tid = threadIdx.x;
    const int wg = blockIdx.x;

    // ---- one-time election: discover XCD, rank within XCD, uniformity.
    // Bounded: grid=256 at 1 WG/CU on 256 CUs is co-resident, and every WG
    // increments ctl[8] exactly once -> the spin terminates.
    if (tid == 0) {
        unsigned x;
        asm volatile("s_getreg_b32 %0, hwreg(HW_REG_XCC_ID)" : "=s"(x));
        x &= 7u;
        unsigned rk = __hip_atomic_fetch_add(&ctl[x], 1u, __ATOMIC_RELAXED,
                                             __HIP_MEMORY_SCOPE_AGENT);
        __hip_atomic_fetch_add(&ctl[8], 1u, __ATOMIC_RELEASE,
                               __HIP_MEMORY_SCOPE_AGENT);
        while (__hip_atomic_load(&ctl[8], __ATOMIC_ACQUIRE,
                                 __HIP_MEMORY_SCOPE_AGENT) < (unsigned)NWG)
            __builtin_amdgcn_s_sleep(2);
        int fast = 1;
        for (int k = 0; k < 8; ++k)
            fast &= (__hip_atomic_load(&ctl[k], __ATOMIC_RELAXED,
                                       __HIP_MEMORY_SCOPE_AGENT) == 32u);
        sh_xcd = (int)x; sh_rank = (int)rk; sh_fast = fast;
    }
    __syncthreads();
    const int xcd = sh_xcd, rank = sh_rank, use_fast = sh_fast;

    if (use_fast && rank < 32) {
        // ================= FAST PATH: per-XCD replica =================
        const int lane = tid & 63;
        const int wv = tid >> 6;           // wave 0..3
        const int wgrow = rank * 64;       // this WG's 64 rows
        unsigned* hxl = hx + (size_t)xcd * 2 * H_DIM;   // local replica buffer

        // weights -> REGISTERS via self-contained asm (loads + wait in ONE
        // block: outputs valid at asm end, spill-safe, non-rematerializable).
        // thread(wv,lane) holds rows wgrow+wv*16+i (i<16), cols lane*8+j*512.
        half8 w[16][4];
        {
            const _Float16* wb = Whh + (size_t)(wgrow + wv * 16) * H_DIM + lane * 8;
            #pragma unroll
            for (int i = 0; i < 16; ++i) {
                const half8* rp = (const half8*)(wb + (size_t)i * H_DIM);
                asm volatile(
                    "global_load_dwordx4 %0, %4, off\n\t"
                    "global_load_dwordx4 %1, %5, off\n\t"
                    "global_load_dwordx4 %2, %6, off\n\t"
                    "global_load_dwordx4 %3, %7, off\n\t"
                    "s_waitcnt vmcnt(0)"
                    : "=&v"(w[i][0]), "=&v"(w[i][1]), "=&v"(w[i][2]), "=&v"(w[i][3])
                    : "v"(rp), "v"(rp + 64), "v"(rp + 128), "v"(rp + 192));
            }
        }
        if (tid < 64) xilds[0][tid] = xi[wgrow + tid];
        __syncthreads();

        // bit-reversed row owned by publishing lane (lane<16)
        const int lr = ((lane & 1) << 3) | (((lane >> 1) & 1) << 2) |
                       (((lane >> 2) & 1) << 1) | ((lane >> 3) & 1);

        for (int t = 0; t < S_LEN; ++t) {
            float xnext = 0.f;
            if (tid < 64 && t + 1 < S_LEN)
                xnext = xi[(size_t)(t + 1) * H_DIM + wgrow + tid];

            // [A] poll the 8 tagged words this thread stages (validated R0:
            // sc0 nt fast rounds; nt is LOAD-BEARING — bare sc0 reads stale
            // clean lines. Escalate to sc0 sc1 (IF truth) after 24 rounds.
            const uint4a* p = (const uint4a*)(hxl + (size_t)(t & 1) * H_DIM) + tid * 2;
            const unsigned tg = (unsigned)t;
            uint4a a, b;
            int rounds = 0;
            for (;;) {
                if (rounds < 24) {
                    asm volatile(
                        "global_load_dwordx4 %0, %2, off sc0 nt\n\t"
                        "global_load_dwordx4 %1, %3, off sc0 nt\n\t"
                        "s_waitcnt vmcnt(0)"
                        : "=&v"(a), "=&v"(b) : "v"(p), "v"(p + 1) : "memory");
                } else {
                    asm volatile(
                        "global_load_dwordx4 %0, %2, off sc0 sc1\n\t"
                        "global_load_dwordx4 %1, %3, off sc0 sc1\n\t"
                        "s_waitcnt vmcnt(0)"
                        : "=&v"(a), "=&v"(b) : "v"(p), "v"(p + 1) : "memory");
                }
                bool ok = TAGOK(a, b);
                if (ok) break;
                ++rounds;
                if (rounds > 2) __builtin_amdgcn_s_sleep(1);
            }
            uint4a hp;
            hp.x = (a.x & 0xffffu) | (a.y << 16);
            hp.y = (a.z & 0xffffu) | (a.w << 16);
            hp.z = (b.x & 0xffffu) | (b.y << 16);
            hp.w = (b.z & 0xffffu) | (b.w << 16);
            *(uint4a*)&hlds[t & 1][tid * 8] = hp;
            if (tid < 64) xilds[(t + 1) & 1][tid] = xnext;
            __syncthreads();

            // [B] h slice (shared across this thread's 16 rows): 4x ds_read_b128
            half8 hv[4];
            {
                const half8* hb = (const half8*)&hlds[t & 1][lane * 8];
                #pragma unroll
                for (int j = 0; j < 4; ++j) hv[j] = hb[j * 64];
            }
            float acc[16];
            #pragma unroll
            for (int i = 0; i < 16; ++i) {
                float s = 0.f;
                #pragma unroll
                for (int j = 0; j < 4; ++j) s = dot8(w[i][j], hv[j], s);
                acc[i] = s;
            }

            // [C] register butterfly; after xor 1,2,4,8 lane holds the 16-lane
            // sum of row lr; xor16/32 complete the 64-lane sum.
            {
                bool hi = lane & 1;
                #pragma unroll
                for (int i = 0; i < 8; ++i) {
                    float snd = hi ? acc[i] : acc[i + 8];
                    float kp  = hi ? acc[i + 8] : acc[i];
                    acc[i] = kp + __shfl_xor(snd, 1);
                }
                hi = lane & 2;
                #pragma unroll
                for (int i = 0; i < 4; ++i) {
                    float snd = hi ? acc[i] : acc[i + 4];
                    float kp  = hi ? acc[i + 4] : acc[i];
                    acc[i] = kp + __shfl_xor(snd, 2);
                }
                hi = lane & 4;
                #pragma unroll
                for (int i = 0; i < 2; ++i) {
                    float snd = hi ? acc[i] : acc[i + 2];
                    float kp  = hi ? acc[i + 2] : acc[i];
                    acc[i] = kp + __shfl_xor(snd, 4);
                }
                hi = lane & 8;
                {
                    float snd = hi ? acc[0] : acc[1];
                    float kp  = hi ? acc[1] : acc[0];
                    acc[0] = kp + __shfl_xor(snd, 8);
                }
                acc[0] += __shfl_xor(acc[0], 16);
                acc[0] += __shfl_xor(acc[0], 32);
            }

            // [D] publish h_{t+1} rows (lanes 0..15 of each wave) — validated
            // sc0 sc1 write-through: updates local L2 en route, reaches IF.
            if (lane < 16) {
                int lrow = wv * 16 + lr;                 // 0..63 within WG
                float hvf = fast_tanh(xilds[t & 1][lrow] + acc[0]);
                _Float16 hf = (_Float16)hvf;
                unsigned pk = ((unsigned)(t + 1) << 16)
                            | (unsigned)__builtin_bit_cast(unsigned short, hf);
                unsigned* dst = hxl + (size_t)((t + 1) & 1) * H_DIM + wgrow + lrow;
                asm volatile("global_store_dword %0, %1, off sc0 sc1"
                             :: "v"(dst), "v"(pk) : "memory");
                if (xcd == 0)
                    rnn[(size_t)t * H_DIM + wgrow + lrow] = hf;
            }
        }
    } else {
        // ================= FALLBACK: global replica (validated) =====
        const int rowbase = wg * RPW;
        const int r = tid >> 5;
        const int j = tid & 31;
        half8 wreg[8];
        {
            const half8* wrow = (const half8*)(Whh + (size_t)(rowbase + r) * H_DIM);
            #pragma unroll
            for (int c = 0; c < 8; ++c) wreg[c] = wrow[j + c * 32];
        }
        if (tid < RPW) xilds[0][tid] = xi[rowbase + tid];
        __syncthreads();

        for (int t = 0; t < S_LEN; ++t) {
            float xnext = 0.f;
            if (tid < RPW && t + 1 < S_LEN)
                xnext = xi[(size_t)(t + 1) * H_DIM + rowbase + tid];

            const uint4a* p0 = (const uint4a*)(hpk + (size_t)(t & 1) * H_DIM) + tid * 2;
            const unsigned tg = (unsigned)t;
            uint4a a = {}, b = {};
            bool got0 = false, got1 = false;
            int round = 0;
            for (;;) {
                if (!got0)
                    asm volatile("global_load_dwordx4 %0, %1, off sc0 sc1"
                                 : "=v"(a) : "v"(p0) : "memory");
                if (!got1)
                    asm volatile("global_load_dwordx4 %0, %1, off sc0 sc1"
                                 : "=v"(b) : "v"(p0 + 1) : "memory");
                asm volatile("s_waitcnt vmcnt(0)" ::: "memory");
                got0 = got0 | (((a.x >> 16) == tg) & ((a.y >> 16) == tg) &
                               ((a.z >> 16) == tg) & ((a.w >> 16) == tg));
                got1 = got1 | (((b.x >> 16) == tg) & ((b.y >> 16) == tg) &
                               ((b.z >> 16) == tg) & ((b.w >> 16) == tg));
                if (got0 && got1) break;
                if (++round > 1) __builtin_amdgcn_s_sleep(1);
            }
            uint4a hp;
            hp.x = (a.x & 0xffffu) | (a.y << 16);
            hp.y = (a.z & 0xffffu) | (a.w << 16);
            hp.z = (b.x & 0xffffu) | (b.y << 16);
            hp.w = (b.z & 0xffffu) | (b.w << 16);
            *(uint4a*)&hlds[t & 1][tid * 8] = hp;
            if (tid < RPW) xilds[(t + 1) & 1][tid] = xnext;
            __syncthreads();

            float acc = 0.f;
            const _Float16* hpt = &hlds[t & 1][j * 8];
            #pragma unroll
            for (int c = 0; c < 8; ++c) {
                half8 hvv = *(const half8*)(hpt + c * 256);
                acc = dot8(wreg[c], hvv, acc);
            }
            acc += __shfl_xor(acc, 1);  acc += __shfl_xor(acc, 2);
            acc += __shfl_xor(acc, 4);  acc += __shfl_xor(acc, 8);
            acc += __shfl_xor(acc, 16);

            if (j == 0) {
                float hvf = fast_tanh(xilds[t & 1][r] + acc);
                _Float16 hf = (_Float16)hvf;
                unsigned pk = ((unsigned)(t + 1) << 16)
                            | (unsigned)__builtin_bit_cast(unsigned short, hf);
                __hip_atomic_store(&hpk[(size_t)((t + 1) & 1) * H_DIM + rowbase + r], pk,
                                   __ATOMIC_RELAXED, __HIP_MEMORY_SCOPE_AGENT);
                rnn[(size_t)t * H_DIM + rowbase + r] = hf;
            }
        }
    }
}

// ---------------- K3: head GEMM + log_softmax
__global__ __launch_bounds__(256) void head_kernel(
        const _Float16* __restrict__ rnn, const _Float16* __restrict__ Wout,
        const float* __restrict__ bout, float* __restrict__ out) {
    __shared__ __align__(16) _Float16 h8[8][H_DIM];
    __shared__ __align__(16) _Float16 wr[H_DIM];
    __shared__ float tl[8][T_TAGS];
    int tid = threadIdx.x;
    size_t sbase = (size_t)blockIdx.x * 8;
    {
        const uint4* src = (const uint4*)(rnn + sbase * H_DIM);
        uint4* dst = (uint4*)&h8[0][0];
        for (int i = tid; i < 8 * H_DIM / 8; i += 256) dst[i] = src[i];
    }
    __syncthreads();
    int sl = ((tid >> 6) << 1) | ((tid >> 5) & 1);
    int l32 = tid & 31;
    for (int t = 0; t < T_TAGS; ++t) {
        ((uint4*)wr)[tid] = ((const uint4*)(Wout + t * H_DIM))[tid];
        __syncthreads();
        float acc = 0.f;
        const _Float16* hp = &h8[sl][l32 * 64];
        const _Float16* wp = &wr[l32 * 64];
        #pragma unroll
        for (int c = 0; c < 8; ++c)
            acc = dot8(*(const half8*)(hp + c * 8), *(const half8*)(wp + c * 8), acc);
        acc += __shfl_xor(acc, 1);  acc += __shfl_xor(acc, 2);
        acc += __shfl_xor(acc, 4);  acc += __shfl_xor(acc, 8);
        acc += __shfl_xor(acc, 16);
        if (l32 == 0) tl[sl][t] = acc + bout[t];
        __syncthreads();
    }
    if (tid < 8) {
        float m = -1e30f;
        for (int t = 0; t < T_TAGS; ++t) m = fmaxf(m, tl[tid][t]);
        float sum = 0.f;
        for (int t = 0; t < T_TAGS; ++t) sum += expf(tl[tid][t] - m);
        float lse = m + logf(sum);
        for (int t = 0; t < T_TAGS; ++t) out[(sbase + tid) * T_TAGS + t] = tl[tid][t] - lse;
    }
}

extern "C" void kernel_launch(void* const* d_in, const int* in_sizes, int n_in,
                              void* d_out, int out_size, void* d_ws, size_t ws_size,
                              hipStream_t stream) {
    const int*   sent = (const int*)  d_in[0];
    const float* emb  = (const float*)d_in[1];
    const float* wih  = (const float*)d_in[2];
    const float* whh  = (const float*)d_in[3];
    const float* bih  = (const float*)d_in[4];
    const float* bhh  = (const float*)d_in[5];
    const float* wout = (const float*)d_in[6];
    const float* bout = (const float*)d_in[7];
    const float* h0   = (const float*)d_in[8];

    char* ws = (char*)d_ws;
    _Float16*       whh_h  = (_Float16*)      (ws + 0);           //  8 MB
    unsigned short* wih_b  = (unsigned short*)(ws + 8388608);     //  4 MB
    _Float16*       wout_h = (_Float16*)      (ws + 12582912);    //  256 KB
    unsigned short* X_b    = (unsigned short*)(ws + 12845056);    //  16 MB
    unsigned*       hx     = (unsigned*)      (ws + 13000704);    //  128 KB, aliases X_b (dead after xi_gemm)
    unsigned*       hpk    = (unsigned*)      (ws + 29605888);    //  16 KB, aliases X_b tail
    float*          xi     = (float*)         (ws + 29622272);    //  64 MB
    _Float16*       rnn    = (_Float16*)      (ws + 96731136);    //  32 MB
    unsigned*       ctl    = (unsigned*)      (ws + 130285568);   //  64 B election counters

    hipMemsetAsync(ctl, 0, 64, stream);
    {
        const int total = H_DIM * H_DIM + H_DIM * E_DIM + 64 * H_DIM;
        cast_kernel<<<(total + 255) / 256, 256, 0, stream>>>(
            whh, wih, wout, whh_h, wih_b, wout_h);
    }
    embed_kernel<<<(S_LEN * E_DIM) / 256, 256, 0, stream>>>(sent, emb, X_b);
    xi_gemm<<<dim3(H_DIM / 16, S_LEN / 64), 256, 0, stream>>>(X_b, wih_b, bih, bhh, xi);
    init_hpk<<<H_DIM / 256, 256, 0, stream>>>(h0, hpk, hx);
    rnn_seq<<<NWG, 256, 0, stream>>>(whh_h, xi, hpk, hx, ctl, rnn);
    head_kernel<<<S_LEN / 8, 256, 0, stream>>>(rnn, wout_h, bout, (float*)d_out);
}

// Round 8
// 25321.677 us; speedup vs baseline: 7.8872x; 1.0702x over previous
//
#include <hip/hip_runtime.h>
#include <hip/hip_bf16.h>

#define S_LEN 8192
#define E_DIM 1024
#define H_DIM 2048
#define T_TAGS 50
#define NWG 256            // persistent workgroups for the recurrence
#define RPW (H_DIM / NWG)  // fallback path: 8 rows per WG

typedef short short8 __attribute__((ext_vector_type(8)));
typedef float floatx4 __attribute__((ext_vector_type(4)));
typedef _Float16 half8 __attribute__((ext_vector_type(8)));
typedef _Float16 half2v __attribute__((ext_vector_type(2)));
typedef unsigned int uint4a __attribute__((ext_vector_type(4)));

__device__ __forceinline__ unsigned short f2bf(float f) {
    unsigned u = __builtin_bit_cast(unsigned, f);
    unsigned r = (u + 0x7fffu + ((u >> 16) & 1u)) >> 16;
    return (unsigned short)r;
}

__device__ __forceinline__ float dot8(half8 a, half8 b, float acc) {
#if __has_builtin(__builtin_amdgcn_fdot2)
    union U { half8 v; half2v p[4]; };
    U ua; ua.v = a; U ub; ub.v = b;
    acc = __builtin_amdgcn_fdot2(ua.p[0], ub.p[0], acc, false);
    acc = __builtin_amdgcn_fdot2(ua.p[1], ub.p[1], acc, false);
    acc = __builtin_amdgcn_fdot2(ua.p[2], ub.p[2], acc, false);
    acc = __builtin_amdgcn_fdot2(ua.p[3], ub.p[3], acc, false);
#else
    #pragma unroll
    for (int i = 0; i < 8; ++i) acc += (float)a[i] * (float)b[i];
#endif
    return acc;
}

__device__ __forceinline__ float fast_tanh(float x) {
    float xc = fminf(fmaxf(x, -9.f), 9.f);
    float e = __expf(2.f * xc);
    return (e - 1.f) / (e + 1.f);
}

#define TAGOK(A, B)                                                          \
    (((A.x >> 16) == tg) & ((A.y >> 16) == tg) & ((A.z >> 16) == tg) &       \
     ((A.w >> 16) == tg) & ((B.x >> 16) == tg) & ((B.y >> 16) == tg) &       \
     ((B.z >> 16) == tg) & ((B.w >> 16) == tg))

// ---------------- K0a: cast weights (W_hh->f16, W_ih->bf16, W_out->f16 padded)
__global__ __launch_bounds__(256) void cast_kernel(
        const float* __restrict__ whh, const float* __restrict__ wih,
        const float* __restrict__ wout,
        _Float16* __restrict__ whh_h, unsigned short* __restrict__ wih_b,
        _Float16* __restrict__ wout_h) {
    const int nWhh = H_DIM * H_DIM;
    const int nWih = H_DIM * E_DIM;
    const int nWout = 64 * H_DIM;
    long long i = (long long)blockIdx.x * 256 + threadIdx.x;
    if (i < nWhh) { whh_h[i] = (_Float16)whh[i]; return; }
    i -= nWhh;
    if (i < nWih) { wih_b[i] = f2bf(wih[i]); return; }
    i -= nWih;
    if (i < nWout) {
        int r = (int)(i >> 11), c = (int)(i & 2047);
        wout_h[i] = (r < T_TAGS) ? (_Float16)wout[r * H_DIM + c] : (_Float16)0.f;
    }
}

// ---------------- K0b: embedding gather -> bf16 X
__global__ __launch_bounds__(256) void embed_kernel(
        const int* __restrict__ sent, const float* __restrict__ emb,
        unsigned short* __restrict__ Xb) {
    size_t i = (size_t)blockIdx.x * 256 + threadIdx.x;
    size_t s = i >> 10, e = i & 1023;
    Xb[i] = f2bf(emb[(size_t)sent[s] * E_DIM + e]);
}

// ---------------- K1: xi = X @ W_ih^T + b_ih + b_hh   (bf16 MFMA)
__global__ __launch_bounds__(256) void xi_gemm(
        const unsigned short* __restrict__ Xb, const unsigned short* __restrict__ Wb,
        const float* __restrict__ bih, const float* __restrict__ bhh,
        float* __restrict__ xi) {
    int lane = threadIdx.x & 63;
    int w = threadIdx.x >> 6;
    int m0 = blockIdx.y * 64 + w * 16;
    int n0 = blockIdx.x * 16;
    int mi = m0 + (lane & 15);
    int ni = n0 + (lane & 15);
    int q8 = (lane >> 4) * 8;
    const short8* arow = (const short8*)(Xb + (size_t)mi * E_DIM + q8);
    const short8* brow = (const short8*)(Wb + (size_t)ni * E_DIM + q8);
    floatx4 acc = {0.f, 0.f, 0.f, 0.f};
    #pragma unroll 4
    for (int k = 0; k < E_DIM / 32; ++k) {
        short8 a = arow[k * 4];
        short8 b = brow[k * 4];
        acc = __builtin_amdgcn_mfma_f32_16x16x32_bf16(a, b, acc, 0, 0, 0);
    }
    float bias = bih[ni] + bhh[ni];
    int rbase = (lane >> 4) * 4;
    #pragma unroll
    for (int i = 0; i < 4; ++i) {
        xi[(size_t)(m0 + rbase + i) * H_DIM + ni] = acc[i] + bias;
    }
}

// ---------------- K1b: init tagged h buffers: global hpk (fallback) + 8 per-XCD
// replicas hx (fast). buf0 = (h0, tag 0); buf1 = never-matching tag.
__global__ __launch_bounds__(256) void init_hpk(
        const float* __restrict__ h0, unsigned* __restrict__ hpk,
        unsigned* __restrict__ hx) {
    int i = blockIdx.x * 256 + threadIdx.x;   // grid covers H_DIM
    if (i < H_DIM) {
        unsigned short hb = __builtin_bit_cast(unsigned short, (_Float16)h0[i]);
        unsigned pk = (unsigned)hb;           // tag 0 in high 16 bits
        hpk[i] = pk;
        hpk[H_DIM + i] = 0xFFFF0000u;
        #pragma unroll
        for (int x = 0; x < 8; ++x) {
            hx[(size_t)x * 2 * H_DIM + i] = pk;
            hx[(size_t)x * 2 * H_DIM + H_DIM + i] = 0xFFFF0000u;
        }
    }
}

// ---------------- K2: persistent sequential recurrence.
// FAST PATH = validated R0 protocol (poll sc0 nt -> escalate sc0 sc1 at >=24;
// publish sc0 sc1 write-through; LDS h staging; ONE barrier/step).
// THIS ROUND: 512-thread WGs so the weight panel FITS in registers.
// R7 evidence: at 256 threads the panel needs 256 VGPRs/thread + ~60 working;
// allocator refused (VGPR_Count=152) and spilled to scratch -> per-step 256
// KB/CU re-read from L2 (~4700cyc ~2us, dominant term of the 3.2us step; same
// cost whether from global-L2 [R0] or scratch-L2 [R7]).
// Now: 8 waves/WG, each thread owns 8 rows x 4 chunks = 128 weight VGPRs,
// ~190 total < the 256 cap from __launch_bounds__(512,2) -> no spill; weights
// truly resident; per-step weight traffic ELIMINATED. Poll shrinks to one
// dwordx4/thread; butterfly is 3 folds (masks 1,2,4; row=bitrev3(lane&7))
// + xor 8,16,32; publish lanes 0..7 of each of 8 waves = 64 rows.
// PROTOCOL HISTORY (measured): R0 ok 3.16us/step; R2 sc0-only store =
// store-buffer limbo (24us); R3 atomic = memory-side at IF (24us); R4
// barrier-free per-wave polls = serialized straggler drains (5.9us).
// FALLBACK (placement skew): validated global protocol; threads>=256 idle
// through the barriers.
__global__ __launch_bounds__(512, 2) void rnn_seq(
        const _Float16* __restrict__ Whh, const float* __restrict__ xi,
        unsigned* __restrict__ hpk, unsigned* __restrict__ hx,
        unsigned* __restrict__ ctl, _Float16* __restrict__ rnn) {
    __shared__ __align__(16) _Float16 hlds[2][H_DIM];     // 8 KB double buffer
    __shared__ float xilds[2][64];
    __shared__ int sh_xcd, sh_rank, sh_fast;
    const int tid = threadIdx.x;
    const int wg = blockIdx.x;

    // ---- one-time election: discover XCD, rank within XCD, uniformity.
    // Bounded: grid=256 at 1 WG/CU on 256 CUs is co-resident, and every WG
    // increments ctl[8] exactly once -> the spin terminates.
    if (tid == 0) {
        unsigned x;
        asm volatile("s_getreg_b32 %0, hwreg(HW_REG_XCC_ID)" : "=s"(x));
        x &= 7u;
        unsigned rk = __hip_atomic_fetch_add(&ctl[x], 1u, __ATOMIC_RELAXED,
                                             __HIP_MEMORY_SCOPE_AGENT);
        __hip_atomic_fetch_add(&ctl[8], 1u, __ATOMIC_RELEASE,
                               __HIP_MEMORY_SCOPE_AGENT);
        while (__hip_atomic_load(&ctl[8], __ATOMIC_ACQUIRE,
                                 __HIP_MEMORY_SCOPE_AGENT) < (unsigned)NWG)
            __builtin_amdgcn_s_sleep(2);
        int fast = 1;
        for (int k = 0; k < 8; ++k)
            fast &= (__hip_atomic_load(&ctl[k], __ATOMIC_RELAXED,
                                       __HIP_MEMORY_SCOPE_AGENT) == 32u);
        sh_xcd = (int)x; sh_rank = (int)rk; sh_fast = fast;
    }
    __syncthreads();
    const int xcd = sh_xcd, rank = sh_rank, use_fast = sh_fast;

    if (use_fast && rank < 32) {
        // ================= FAST PATH: per-XCD replica =================
        const int lane = tid & 63;
        const int wv = tid >> 6;           // wave 0..7
        const int wgrow = rank * 64;       // this WG's 64 rows
        unsigned* hxl = hx + (size_t)xcd * 2 * H_DIM;   // local replica buffer

        // weights -> REGISTERS via self-contained asm (loads + wait in ONE
        // block: outputs valid at asm end, spill-safe, non-rematerializable).
        // thread(wv,lane) owns rows wgrow+wv*8+i (i<8), cols lane*8+j*512.
        // 128 VGPRs of weights; ~190 total fits the 256 cap -> resident.
        half8 w[8][4];
        {
            const _Float16* wb = Whh + (size_t)(wgrow + wv * 8) * H_DIM + lane * 8;
            #pragma unroll
            for (int i = 0; i < 8; ++i) {
                const half8* rp = (const half8*)(wb + (size_t)i * H_DIM);
                asm volatile(
                    "global_load_dwordx4 %0, %4, off\n\t"
                    "global_load_dwordx4 %1, %5, off\n\t"
                    "global_load_dwordx4 %2, %6, off\n\t"
                    "global_load_dwordx4 %3, %7, off\n\t"
                    "s_waitcnt vmcnt(0)"
                    : "=&v"(w[i][0]), "=&v"(w[i][1]), "=&v"(w[i][2]), "=&v"(w[i][3])
                    : "v"(rp), "v"(rp + 64), "v"(rp + 128), "v"(rp + 192));
            }
        }
        if (tid < 64) xilds[0][tid] = xi[wgrow + tid];
        __syncthreads();

        // bit-reversed row (3 bits) owned by publishing lane (lane<8)
        const int lr3 = ((lane & 1) << 2) | (lane & 2) | ((lane >> 2) & 1);
        const int lrow = wv * 8 + lr3;     // 0..63 within WG

        for (int t = 0; t < S_LEN; ++t) {
            float xnext = 0.f;
            if (tid < 64 && t + 1 < S_LEN)
                xnext = xi[(size_t)(t + 1) * H_DIM + wgrow + tid];

            // [A] poll the 4 tagged words this thread stages (validated R0:
            // sc0 nt fast rounds; nt is LOAD-BEARING — bare sc0 reads stale
            // clean lines. Escalate to sc0 sc1 (IF truth) after 24 rounds.
            const uint4a* p = (const uint4a*)(hxl + (size_t)(t & 1) * H_DIM) + tid;
            const unsigned tg = (unsigned)t;
            uint4a a;
            int rounds = 0;
            for (;;) {
                if (rounds < 24) {
                    asm volatile(
                        "global_load_dwordx4 %0, %1, off sc0 nt\n\t"
                        "s_waitcnt vmcnt(0)"
                        : "=&v"(a) : "v"(p) : "memory");
                } else {
                    asm volatile(
                        "global_load_dwordx4 %0, %1, off sc0 sc1\n\t"
                        "s_waitcnt vmcnt(0)"
                        : "=&v"(a) : "v"(p) : "memory");
                }
                bool ok = ((a.x >> 16) == tg) & ((a.y >> 16) == tg) &
                          ((a.z >> 16) == tg) & ((a.w >> 16) == tg);
                if (ok) break;
                ++rounds;
                if (rounds > 2) __builtin_amdgcn_s_sleep(1);
            }
            {
                uint2 hp2;
                hp2.x = (a.x & 0xffffu) | (a.y << 16);
                hp2.y = (a.z & 0xffffu) | (a.w << 16);
                *(uint2*)&hlds[t & 1][tid * 4] = hp2;
            }
            if (tid < 64) xilds[(t + 1) & 1][tid] = xnext;
            __syncthreads();

            // [B] h slice (shared across this thread's 8 rows): 4x ds_read_b128
            half8 hv[4];
            {
                const half8* hb = (const half8*)&hlds[t & 1][lane * 8];
                #pragma unroll
                for (int j = 0; j < 4; ++j) hv[j] = hb[j * 64];
            }
            float acc[8];
            #pragma unroll
            for (int i = 0; i < 8; ++i) {
                float s = 0.f;
                #pragma unroll
                for (int j = 0; j < 4; ++j) s = dot8(w[i][j], hv[j], s);
                acc[i] = s;
            }

            // [C] register butterfly: folds (masks 1,2,4) leave lane holding
            // row bitrev3(lane&7) summed over its 8-lane group; xor 8,16,32
            // complete the 64-lane sum.
            {
                bool hi = lane & 1;
                #pragma unroll
                for (int i = 0; i < 4; ++i) {
                    float snd = hi ? acc[i] : acc[i + 4];
                    float kp  = hi ? acc[i + 4] : acc[i];
                    acc[i] = kp + __shfl_xor(snd, 1);
                }
                hi = lane & 2;
                #pragma unroll
                for (int i = 0; i < 2; ++i) {
                    float snd = hi ? acc[i] : acc[i + 2];
                    float kp  = hi ? acc[i + 2] : acc[i];
                    acc[i] = kp + __shfl_xor(snd, 2);
                }
                hi = lane & 4;
                {
                    float snd = hi ? acc[0] : acc[1];
                    float kp  = hi ? acc[1] : acc[0];
                    acc[0] = kp + __shfl_xor(snd, 4);
                }
                acc[0] += __shfl_xor(acc[0], 8);
                acc[0] += __shfl_xor(acc[0], 16);
                acc[0] += __shfl_xor(acc[0], 32);
            }

            // [D] publish h_{t+1} rows (lanes 0..7 of each of 8 waves) —
            // validated sc0 sc1 write-through: local L2 en route, reaches IF.
            if (lane < 8) {
                float hvf = fast_tanh(xilds[t & 1][lrow] + acc[0]);
                _Float16 hf = (_Float16)hvf;
                unsigned pk = ((unsigned)(t + 1) << 16)
                            | (unsigned)__builtin_bit_cast(unsigned short, hf);
                unsigned* dst = hxl + (size_t)((t + 1) & 1) * H_DIM + wgrow + lrow;
                asm volatile("global_store_dword %0, %1, off sc0 sc1"
                             :: "v"(dst), "v"(pk) : "memory");
                if (xcd == 0)
                    rnn[(size_t)t * H_DIM + wgrow + lrow] = hf;
            }
        }
    } else {
        // ========= FALLBACK: global replica (validated protocol). =========
        // Work done by tid<256 exactly as the validated 256-thread version;
        // threads 256..511 only participate in the barriers.
        const int rowbase = wg * RPW;
        const int r = (tid & 255) >> 5;
        const int j = tid & 31;
        half8 wreg[8];
        if (tid < 256) {
            const half8* wrow = (const half8*)(Whh + (size_t)(rowbase + r) * H_DIM);
            #pragma unroll
            for (int c = 0; c < 8; ++c) wreg[c] = wrow[j + c * 32];
        }
        if (tid < RPW) xilds[0][tid] = xi[rowbase + tid];
        __syncthreads();

        for (int t = 0; t < S_LEN; ++t) {
            float xnext = 0.f;
            if (tid < RPW && t + 1 < S_LEN)
                xnext = xi[(size_t)(t + 1) * H_DIM + rowbase + tid];

            if (tid < 256) {
                const uint4a* p0 = (const uint4a*)(hpk + (size_t)(t & 1) * H_DIM) + tid * 2;
                const unsigned tg = (unsigned)t;
                uint4a a = {}, b = {};
                bool got0 = false, got1 = false;
                int round = 0;
                for (;;) {
                    if (!got0)
                        asm volatile("global_load_dwordx4 %0, %1, off sc0 sc1"
                                     : "=v"(a) : "v"(p0) : "memory");
                    if (!got1)
                        asm volatile("global_load_dwordx4 %0, %1, off sc0 sc1"
                                     : "=v"(b) : "v"(p0 + 1) : "memory");
                    asm volatile("s_waitcnt vmcnt(0)" ::: "memory");
                    got0 = got0 | (((a.x >> 16) == tg) & ((a.y >> 16) == tg) &
                                   ((a.z >> 16) == tg) & ((a.w >> 16) == tg));
                    got1 = got1 | (((b.x >> 16) == tg) & ((b.y >> 16) == tg) &
                                   ((b.z >> 16) == tg) & ((b.w >> 16) == tg));
                    if (got0 && got1) break;
                    if (++round > 1) __builtin_amdgcn_s_sleep(1);
                }
                uint4a hp;
                hp.x = (a.x & 0xffffu) | (a.y << 16);
                hp.y = (a.z & 0xffffu) | (a.w << 16);
                hp.z = (b.x & 0xffffu) | (b.y << 16);
                hp.w = (b.z & 0xffffu) | (b.w << 16);
                *(uint4a*)&hlds[t & 1][tid * 8] = hp;
            }
            if (tid < RPW) xilds[(t + 1) & 1][tid] = xnext;
            __syncthreads();

            if (tid < 256) {
                float acc = 0.f;
                const _Float16* hpt = &hlds[t & 1][j * 8];
                #pragma unroll
                for (int c = 0; c < 8; ++c) {
                    half8 hvv = *(const half8*)(hpt + c * 256);
                    acc = dot8(wreg[c], hvv, acc);
                }
                acc += __shfl_xor(acc, 1);  acc += __shfl_xor(acc, 2);
                acc += __shfl_xor(acc, 4);  acc += __shfl_xor(acc, 8);
                acc += __shfl_xor(acc, 16);

                if (j == 0) {
                    float hvf = fast_tanh(xilds[t & 1][r] + acc);
                    _Float16 hf = (_Float16)hvf;
                    unsigned pk = ((unsigned)(t + 1) << 16)
                                | (unsigned)__builtin_bit_cast(unsigned short, hf);
                    __hip_atomic_store(&hpk[(size_t)((t + 1) & 1) * H_DIM + rowbase + r], pk,
                                       __ATOMIC_RELAXED, __HIP_MEMORY_SCOPE_AGENT);
                    rnn[(size_t)t * H_DIM + rowbase + r] = hf;
                }
            }
        }
    }
}

// ---------------- K3: head GEMM + log_softmax
__global__ __launch_bounds__(256) void head_kernel(
        const _Float16* __restrict__ rnn, const _Float16* __restrict__ Wout,
        const float* __restrict__ bout, float* __restrict__ out) {
    __shared__ __align__(16) _Float16 h8[8][H_DIM];
    __shared__ __align__(16) _Float16 wr[H_DIM];
    __shared__ float tl[8][T_TAGS];
    int tid = threadIdx.x;
    size_t sbase = (size_t)blockIdx.x * 8;
    {
        const uint4* src = (const uint4*)(rnn + sbase * H_DIM);
        uint4* dst = (uint4*)&h8[0][0];
        for (int i = tid; i < 8 * H_DIM / 8; i += 256) dst[i] = src[i];
    }
    __syncthreads();
    int sl = ((tid >> 6) << 1) | ((tid >> 5) & 1);
    int l32 = tid & 31;
    for (int t = 0; t < T_TAGS; ++t) {
        ((uint4*)wr)[tid] = ((const uint4*)(Wout + t * H_DIM))[tid];
        __syncthreads();
        float acc = 0.f;
        const _Float16* hp = &h8[sl][l32 * 64];
        const _Float16* wp = &wr[l32 * 64];
        #pragma unroll
        for (int c = 0; c < 8; ++c)
            acc = dot8(*(const half8*)(hp + c * 8), *(const half8*)(wp + c * 8), acc);
        acc += __shfl_xor(acc, 1);  acc += __shfl_xor(acc, 2);
        acc += __shfl_xor(acc, 4);  acc += __shfl_xor(acc, 8);
        acc += __shfl_xor(acc, 16);
        if (l32 == 0) tl[sl][t] = acc + bout[t];
        __syncthreads();
    }
    if (tid < 8) {
        float m = -1e30f;
        for (int t = 0; t < T_TAGS; ++t) m = fmaxf(m, tl[tid][t]);
        float sum = 0.f;
        for (int t = 0; t < T_TAGS; ++t) sum += expf(tl[tid][t] - m);
        float lse = m + logf(sum);
        for (int t = 0; t < T_TAGS; ++t) out[(sbase + tid) * T_TAGS + t] = tl[tid][t] - lse;
    }
}

extern "C" void kernel_launch(void* const* d_in, const int* in_sizes, int n_in,
                              void* d_out, int out_size, void* d_ws, size_t ws_size,
                              hipStream_t stream) {
    const int*   sent = (const int*)  d_in[0];
    const float* emb  = (const float*)d_in[1];
    const float* wih  = (const float*)d_in[2];
    const float* whh  = (const float*)d_in[3];
    const float* bih  = (const float*)d_in[4];
    const float* bhh  = (const float*)d_in[5];
    const float* wout = (const float*)d_in[6];
    const float* bout = (const float*)d_in[7];
    const float* h0   = (const float*)d_in[8];

    char* ws = (char*)d_ws;
    _Float16*       whh_h  = (_Float16*)      (ws + 0);           //  8 MB
    unsigned short* wih_b  = (unsigned short*)(ws + 8388608);     //  4 MB
    _Float16*       wout_h = (_Float16*)      (ws + 12582912);    //  256 KB
    unsigned short* X_b    = (unsigned short*)(ws + 12845056);    //  16 MB
    unsigned*       hx     = (unsigned*)      (ws + 13000704);    //  128 KB, aliases X_b (dead after xi_gemm)
    unsigned*       hpk    = (unsigned*)      (ws + 29605888);    //  16 KB, aliases X_b tail
    float*          xi     = (float*)         (ws + 29622272);    //  64 MB
    _Float16*       rnn    = (_Float16*)      (ws + 96731136);    //  32 MB
    unsigned*       ctl    = (unsigned*)      (ws + 130285568);   //  64 B election counters

    hipMemsetAsync(ctl, 0, 64, stream);
    {
        const int total = H_DIM * H_DIM + H_DIM * E_DIM + 64 * H_DIM;
        cast_kernel<<<(total + 255) / 256, 256, 0, stream>>>(
            whh, wih, wout, whh_h, wih_b, wout_h);
    }
    embed_kernel<<<(S_LEN * E_DIM) / 256, 256, 0, stream>>>(sent, emb, X_b);
    xi_gemm<<<dim3(H_DIM / 16, S_LEN / 64), 256, 0, stream>>>(X_b, wih_b, bih, bhh, xi);
    init_hpk<<<H_DIM / 256, 256, 0, stream>>>(h0, hpk, hx);
    rnn_seq<<<NWG, 512, 0, stream>>>(whh_h, xi, hpk, hx, ctl, rnn);
    head_kernel<<<S_LEN / 8, 256, 0, stream>>>(rnn, wout_h, bout, (float*)d_out);
}